// Round 2
// baseline (11408.936 us; speedup 1.0000x reference)
//
#include <hip/hip_runtime.h>
#include <math.h>

#define BB  4
#define NN  2000
#define TT  24
#define FIN 16
#define HH  128
#define EE  64000
#define CC  6
#define BN  (BB*NN)   // 8000

// ---------------- prep kernels ----------------
__global__ void transpose_kernel(const float* __restrict__ in, float* __restrict__ out,
                                 int R, int C) {
    int idx = blockIdx.x * 256 + threadIdx.x;
    if (idx < R * C) {
        int r = idx / C, c = idx - r * C;
        out[c * R + r] = in[idx];
    }
}

// W_hh[(g*128+j)][k]  ->  Wt4[(k>>2)][g][j][k&3]   (float4-loadable, coalesced over j)
__global__ void pack_whh_kernel(const float* __restrict__ W_hh, float* __restrict__ Wt4) {
    int idx = blockIdx.x * 256 + threadIdx.x;
    if (idx < 384 * 128) {
        int gi = idx >> 7;        // 0..383 (gate output row)
        int k  = idx & 127;       // 0..127 (input h index)
        int g  = gi >> 7;         // 0..2
        int j  = gi & 127;        // 0..127
        Wt4[(k >> 2) * 1536 + g * 512 + j * 4 + (k & 3)] = W_hh[idx];
    }
}

__global__ void cnt_kernel(const int* __restrict__ dst, int* __restrict__ cnt) {
    int e = blockIdx.x * 256 + threadIdx.x;
    if (e < EE) atomicAdd(&cnt[dst[e]], 1);
}

__global__ __launch_bounds__(256) void scan_kernel(const int* __restrict__ cnt,
                                                   int* __restrict__ rowptr,
                                                   int* __restrict__ cursor) {
    __shared__ int part[256];
    int tid = threadIdx.x;
    int base = tid * 8;
    int loc[8]; int s = 0;
    #pragma unroll
    for (int u = 0; u < 8; ++u) {
        int v = (base + u < NN) ? cnt[base + u] : 0;
        loc[u] = s; s += v;
    }
    part[tid] = s;
    __syncthreads();
    #pragma unroll
    for (int off = 1; off < 256; off <<= 1) {
        int add = (tid >= off) ? part[tid - off] : 0;
        __syncthreads();
        part[tid] += add;
        __syncthreads();
    }
    int offset = (tid > 0) ? part[tid - 1] : 0;
    #pragma unroll
    for (int u = 0; u < 8; ++u) {
        int idx = base + u;
        if (idx < NN) { rowptr[idx] = offset + loc[u]; cursor[idx] = offset + loc[u]; }
    }
    if (tid == 255) rowptr[NN] = part[255];
}

__global__ void dis_kernel(const int* __restrict__ cnt, float* __restrict__ dis) {
    int n = blockIdx.x * 256 + threadIdx.x;
    if (n < NN) dis[n] = rsqrtf(fmaxf((float)cnt[n], 1.0f));
}

__global__ void csr_fill_kernel(const int* __restrict__ src, const int* __restrict__ dst,
                                const float* __restrict__ dis, int* __restrict__ cursor,
                                int* __restrict__ esrc, float* __restrict__ enorm) {
    int e = blockIdx.x * 256 + threadIdx.x;
    if (e < EE) {
        int d = dst[e], s = src[e];
        int pos = atomicAdd(&cursor[d], 1);
        esrc[pos] = s;
        enorm[pos] = dis[s] * dis[d];
    }
}

// ---------------- GRU ----------------
#define K1(wr,wz,wn,kidx) do { \
    float4 h0_ = *(const float4*)&hs[kidx][0]; \
    float4 h1_ = *(const float4*)&hs[kidx][4]; \
    ar[0]=fmaf((wr),h0_.x,ar[0]); ar[1]=fmaf((wr),h0_.y,ar[1]); ar[2]=fmaf((wr),h0_.z,ar[2]); ar[3]=fmaf((wr),h0_.w,ar[3]); \
    ar[4]=fmaf((wr),h1_.x,ar[4]); ar[5]=fmaf((wr),h1_.y,ar[5]); ar[6]=fmaf((wr),h1_.z,ar[6]); ar[7]=fmaf((wr),h1_.w,ar[7]); \
    az[0]=fmaf((wz),h0_.x,az[0]); az[1]=fmaf((wz),h0_.y,az[1]); az[2]=fmaf((wz),h0_.z,az[2]); az[3]=fmaf((wz),h0_.w,az[3]); \
    az[4]=fmaf((wz),h1_.x,az[4]); az[5]=fmaf((wz),h1_.y,az[5]); az[6]=fmaf((wz),h1_.z,az[6]); az[7]=fmaf((wz),h1_.w,az[7]); \
    an[0]=fmaf((wn),h0_.x,an[0]); an[1]=fmaf((wn),h0_.y,an[1]); an[2]=fmaf((wn),h0_.z,an[2]); an[3]=fmaf((wn),h0_.w,an[3]); \
    an[4]=fmaf((wn),h1_.x,an[4]); an[5]=fmaf((wn),h1_.y,an[5]); an[6]=fmaf((wn),h1_.z,an[6]); an[7]=fmaf((wn),h1_.w,an[7]); \
} while(0)

#define COMPUTE8(base, R0,R1,Z0,Z1,N0,N1) do { \
    K1(R0.x,Z0.x,N0.x,(base)+0); K1(R0.y,Z0.y,N0.y,(base)+1); \
    K1(R0.z,Z0.z,N0.z,(base)+2); K1(R0.w,Z0.w,N0.w,(base)+3); \
    K1(R1.x,Z1.x,N1.x,(base)+4); K1(R1.y,Z1.y,N1.y,(base)+5); \
    K1(R1.z,Z1.z,N1.z,(base)+6); K1(R1.w,Z1.w,N1.w,(base)+7); \
} while(0)

__global__ __launch_bounds__(128, 2) void gru_kernel(
    const float* __restrict__ x,       // [BN][TT][FIN]
    const float* __restrict__ Wt4,     // packed, see pack_whh_kernel
    const float* __restrict__ W_ih,    // [384][FIN]
    const float* __restrict__ b_ih, const float* __restrict__ b_hh,
    float* __restrict__ temporal)      // [BN][HH]
{
    const int j = threadIdx.x;
    const int seq0 = blockIdx.x * 8;

    __shared__ __align__(16) float xs[TT][8][FIN];  // 12 KB
    __shared__ __align__(16) float hs[HH][8];       // 4 KB

    const float* xg = x + (size_t)seq0 * TT * FIN;
    for (int i = j; i < 8 * TT * FIN; i += 128) {
        int s = i / (TT * FIN);
        int rem = i - s * (TT * FIN);
        int t = rem / FIN;
        int f = rem - t * FIN;
        xs[t][s][f] = xg[i];
    }
    #pragma unroll
    for (int s = 0; s < 8; ++s) hs[j][s] = 0.0f;

    float wir[FIN], wiz[FIN], win[FIN];
    #pragma unroll
    for (int f = 0; f < FIN; ++f) {
        wir[f] = W_ih[(j      ) * FIN + f];
        wiz[f] = W_ih[(j + 128) * FIN + f];
        win[f] = W_ih[(j + 256) * FIN + f];
    }
    const float bir = b_ih[j], biz = b_ih[j + 128], bin_ = b_ih[j + 256];
    const float bhr = b_hh[j], bhz = b_hh[j + 128], bhn = b_hh[j + 256];

    const float4* __restrict__ Wv = (const float4*)Wt4;  // [(k>>2)*384 + g*128 + j]

    __syncthreads();

    for (int t = 0; t < TT; ++t) {
        // issue first hh prefetch (chunks 0,1 = k 0..7)
        float4 rA0 = Wv[0*384 +       j], rA1 = Wv[1*384 +       j];
        float4 zA0 = Wv[0*384 + 128 + j], zA1 = Wv[1*384 + 128 + j];
        float4 nA0 = Wv[0*384 + 256 + j], nA1 = Wv[1*384 + 256 + j];

        // ih GEMV (hides prefetch latency)
        float gr[8], gz[8], gn[8];
        #pragma unroll
        for (int s = 0; s < 8; ++s) { gr[s] = bir; gz[s] = biz; gn[s] = bin_; }
        #pragma unroll
        for (int s = 0; s < 8; ++s) {
            float4 x0 = *(const float4*)&xs[t][s][0];
            float4 x1 = *(const float4*)&xs[t][s][4];
            float4 x2 = *(const float4*)&xs[t][s][8];
            float4 x3 = *(const float4*)&xs[t][s][12];
            float xv[16] = {x0.x, x0.y, x0.z, x0.w, x1.x, x1.y, x1.z, x1.w,
                            x2.x, x2.y, x2.z, x2.w, x3.x, x3.y, x3.z, x3.w};
            #pragma unroll
            for (int f = 0; f < FIN; ++f) {
                gr[s] = fmaf(wir[f], xv[f], gr[s]);
                gz[s] = fmaf(wiz[f], xv[f], gz[s]);
                gn[s] = fmaf(win[f], xv[f], gn[s]);
            }
        }

        float ar[8], az[8], an[8];
        #pragma unroll
        for (int s = 0; s < 8; ++s) { ar[s] = bhr; az[s] = bhz; an[s] = bhn; }

        // hh GEMV: double-buffered register prefetch, 8 k's per buffer
        #pragma unroll
        for (int kk = 0; kk < 128; kk += 16) {
            const int cB = (kk >> 2) + 2;
            float4 rB0 = Wv[cB*384 +       j], rB1 = Wv[(cB+1)*384 +       j];
            float4 zB0 = Wv[cB*384 + 128 + j], zB1 = Wv[(cB+1)*384 + 128 + j];
            float4 nB0 = Wv[cB*384 + 256 + j], nB1 = Wv[(cB+1)*384 + 256 + j];

            COMPUTE8(kk, rA0, rA1, zA0, zA1, nA0, nA1);

            if (kk + 16 < 128) {
                const int cA = (kk >> 2) + 4;
                rA0 = Wv[cA*384 +       j]; rA1 = Wv[(cA+1)*384 +       j];
                zA0 = Wv[cA*384 + 128 + j]; zA1 = Wv[(cA+1)*384 + 128 + j];
                nA0 = Wv[cA*384 + 256 + j]; nA1 = Wv[(cA+1)*384 + 256 + j];
            }

            COMPUTE8(kk + 8, rB0, rB1, zB0, zB1, nB0, nB1);
        }

        float hnew[8];
        #pragma unroll
        for (int s = 0; s < 8; ++s) {
            float vr = gr[s] + ar[s];
            float vz = gz[s] + az[s];
            float r = 1.0f / (1.0f + __expf(-vr));
            float z = 1.0f / (1.0f + __expf(-vz));
            float vn = gn[s] + r * an[s];
            float u = fminf(fmaxf(vn, -20.0f), 20.0f);
            float e2 = __expf(2.0f * u);
            float nn = (e2 - 1.0f) / (e2 + 1.0f);
            hnew[s] = (1.0f - z) * nn + z * hs[j][s];
        }
        __syncthreads();
        #pragma unroll
        for (int s = 0; s < 8; ++s) hs[j][s] = hnew[s];
        __syncthreads();
    }

    #pragma unroll
    for (int s = 0; s < 8; ++s)
        temporal[(size_t)(seq0 + s) * HH + j] = hs[j][s];
}

// ---------------- fused GCN layer: gather + linear + LayerNorm + ReLU ----------------
__global__ __launch_bounds__(128) void gcn_kernel(
    const float* __restrict__ xin,     // [BB][NN][HH]
    const int* __restrict__ rowptr,    // [NN+1]
    const int* __restrict__ esrc,      // edges sorted by dst
    const float* __restrict__ enorm,
    const float* __restrict__ Wt,      // [HH][HH]  Wt[k][j] = W[j][k]
    const float* __restrict__ bias,
    const float* __restrict__ gma, const float* __restrict__ bta,
    float* __restrict__ out)           // [BB][NN][HH]
{
    const int n = blockIdx.x;
    const int j = threadIdx.x;
    const int beg = rowptr[n], end = rowptr[n + 1];

    float a0 = 0.f, a1 = 0.f, a2 = 0.f, a3 = 0.f;
    int e = beg;
    for (; e + 1 < end; e += 2) {
        int   s0 = esrc[e],   s1 = esrc[e + 1];
        float m0 = enorm[e],  m1 = enorm[e + 1];
        const float* p0 = xin + (size_t)s0 * HH + j;
        const float* p1 = xin + (size_t)s1 * HH + j;
        float v00 = p0[0], v01 = p0[NN*HH], v02 = p0[2*NN*HH], v03 = p0[3*NN*HH];
        float v10 = p1[0], v11 = p1[NN*HH], v12 = p1[2*NN*HH], v13 = p1[3*NN*HH];
        a0 = fmaf(m0, v00, a0); a1 = fmaf(m0, v01, a1);
        a2 = fmaf(m0, v02, a2); a3 = fmaf(m0, v03, a3);
        a0 = fmaf(m1, v10, a0); a1 = fmaf(m1, v11, a1);
        a2 = fmaf(m1, v12, a2); a3 = fmaf(m1, v13, a3);
    }
    if (e < end) {
        int s0 = esrc[e]; float m0 = enorm[e];
        const float* p0 = xin + (size_t)s0 * HH + j;
        a0 = fmaf(m0, p0[0],       a0); a1 = fmaf(m0, p0[NN*HH],   a1);
        a2 = fmaf(m0, p0[2*NN*HH], a2); a3 = fmaf(m0, p0[3*NN*HH], a3);
    }

    __shared__ __align__(16) float agg[BB][HH];
    agg[0][j] = a0; agg[1][j] = a1; agg[2][j] = a2; agg[3][j] = a3;
    __syncthreads();

    const float bj = bias[j];
    float c0 = bj, c1 = bj, c2 = bj, c3 = bj;
    #pragma unroll 4
    for (int k = 0; k < HH; ++k) {
        float w = Wt[k * HH + j];
        c0 = fmaf(w, agg[0][k], c0);
        c1 = fmaf(w, agg[1][k], c1);
        c2 = fmaf(w, agg[2][k], c2);
        c3 = fmaf(w, agg[3][k], c3);
    }

    const int lane = j & 63, wid = j >> 6;
    __shared__ float red[2][BB][2];
    const float gj = gma[j], btj = bta[j];

#define LNRED(cv, b) do { \
        float s1 = (cv), s2 = (cv) * (cv); \
        for (int off = 32; off >= 1; off >>= 1) { s1 += __shfl_down(s1, off); s2 += __shfl_down(s2, off); } \
        if (lane == 0) { red[wid][b][0] = s1; red[wid][b][1] = s2; } \
    } while (0)
    LNRED(c0, 0); LNRED(c1, 1); LNRED(c2, 2); LNRED(c3, 3);
    __syncthreads();

#define LNOUT(cv, b) do { \
        float s1 = red[0][b][0] + red[1][b][0]; \
        float s2 = red[0][b][1] + red[1][b][1]; \
        float mu = s1 * (1.0f / HH); \
        float var = s2 * (1.0f / HH) - mu * mu; \
        float y = ((cv) - mu) * rsqrtf(var + 1e-5f) * gj + btj; \
        out[((size_t)(b) * NN + n) * HH + j] = fmaxf(y, 0.0f); \
    } while (0)
    LNOUT(c0, 0); LNOUT(c1, 1); LNOUT(c2, 2); LNOUT(c3, 3);
#undef LNRED
#undef LNOUT
}

// ---------------- classifier (fused 2-layer MLP) ----------------
__global__ __launch_bounds__(128) void classifier_kernel(
    const float* __restrict__ tin,   // temporal [BN][HH]
    const float* __restrict__ sin_,  // spatial  [BN][HH]
    const float* __restrict__ Wt1,   // [2*HH][HH]
    const float* __restrict__ b1,
    const float* __restrict__ W2,    // [CC][HH]
    const float* __restrict__ b2,
    float* __restrict__ out)         // [BN][CC]
{
    const int j = threadIdx.x;
    const int r0 = blockIdx.x * 8;
    __shared__ __align__(16) float tb[HH][8];
    __shared__ __align__(16) float sb[HH][8];
    __shared__ __align__(16) float h1[HH][8];
    for (int i = j; i < 8 * HH; i += 128) {
        int r = i >> 7, k = i & 127;
        tb[k][r] = tin [(size_t)(r0 + r) * HH + k];
        sb[k][r] = sin_[(size_t)(r0 + r) * HH + k];
    }
    __syncthreads();

    float acc[8];
    float bj = b1[j];
    #pragma unroll
    for (int r = 0; r < 8; ++r) acc[r] = bj;
    #pragma unroll 2
    for (int k = 0; k < HH; ++k) {
        float w = Wt1[k * HH + j];
        float4 a  = *(const float4*)&tb[k][0];
        float4 b4 = *(const float4*)&tb[k][4];
        acc[0] = fmaf(w, a.x,  acc[0]); acc[1] = fmaf(w, a.y,  acc[1]);
        acc[2] = fmaf(w, a.z,  acc[2]); acc[3] = fmaf(w, a.w,  acc[3]);
        acc[4] = fmaf(w, b4.x, acc[4]); acc[5] = fmaf(w, b4.y, acc[5]);
        acc[6] = fmaf(w, b4.z, acc[6]); acc[7] = fmaf(w, b4.w, acc[7]);
    }
    #pragma unroll 2
    for (int k = 0; k < HH; ++k) {
        float w = Wt1[(HH + k) * HH + j];
        float4 a  = *(const float4*)&sb[k][0];
        float4 b4 = *(const float4*)&sb[k][4];
        acc[0] = fmaf(w, a.x,  acc[0]); acc[1] = fmaf(w, a.y,  acc[1]);
        acc[2] = fmaf(w, a.z,  acc[2]); acc[3] = fmaf(w, a.w,  acc[3]);
        acc[4] = fmaf(w, b4.x, acc[4]); acc[5] = fmaf(w, b4.y, acc[5]);
        acc[6] = fmaf(w, b4.z, acc[6]); acc[7] = fmaf(w, b4.w, acc[7]);
    }
    #pragma unroll
    for (int r = 0; r < 8; ++r) h1[j][r] = fmaxf(acc[r], 0.0f);
    __syncthreads();

    if (j < 8 * CC) {
        int r = j / CC, c = j - r * CC;
        float a = b2[c];
        for (int k = 0; k < HH; ++k) a = fmaf(W2[c * HH + k], h1[k][r], a);
        out[(size_t)(r0 + r) * CC + c] = a;
    }
}

// ---------------- launch ----------------
extern "C" void kernel_launch(void* const* d_in, const int* in_sizes, int n_in,
                              void* d_out, int out_size, void* d_ws, size_t ws_size,
                              hipStream_t stream) {
    const float* x    = (const float*)d_in[0];
    const int*   ei   = (const int*)  d_in[1];
    const float* W_ih = (const float*)d_in[2];
    const float* W_hh = (const float*)d_in[3];
    const float* b_ih = (const float*)d_in[4];
    const float* b_hh = (const float*)d_in[5];
    const float* gW1  = (const float*)d_in[6];
    const float* gb1  = (const float*)d_in[7];
    const float* gW2  = (const float*)d_in[8];
    const float* gb2  = (const float*)d_in[9];
    const float* lg1  = (const float*)d_in[10];
    const float* lb1  = (const float*)d_in[11];
    const float* lg2  = (const float*)d_in[12];
    const float* lb2  = (const float*)d_in[13];
    const float* cW1  = (const float*)d_in[14];
    const float* cb1  = (const float*)d_in[15];
    const float* cW2  = (const float*)d_in[16];
    const float* cb2  = (const float*)d_in[17];
    float* out = (float*)d_out;

    float* ws = (float*)d_ws;
    float* Wt4   = ws;  ws += 384 * 128;
    float* Wt_g1 = ws;  ws += 128 * 128;
    float* Wt_g2 = ws;  ws += 128 * 128;
    float* Wt_c1 = ws;  ws += 256 * 128;
    float* dis   = ws;  ws += 2048;
    float* enorm = ws;  ws += EE;
    float* temporal = ws; ws += (size_t)BN * HH;
    float* sA    = ws;  ws += (size_t)BN * HH;
    float* sB    = ws;  ws += (size_t)BN * HH;
    int* ip      = (int*)ws;
    int* cnt     = ip;  ip += 2048;
    int* rowptr  = ip;  ip += 2080;
    int* cursor  = ip;  ip += 2048;
    int* esrc    = ip;  ip += EE;

    const int* srcp = ei;
    const int* dstp = ei + EE;

    hipMemsetAsync(cnt, 0, 2048 * sizeof(int), stream);

    pack_whh_kernel<<<192, 256, 0, stream>>>(W_hh, Wt4);
    transpose_kernel<<<64, 256, 0, stream>>>(gW1, Wt_g1, 128, 128);
    transpose_kernel<<<64, 256, 0, stream>>>(gW2, Wt_g2, 128, 128);
    transpose_kernel<<<128, 256, 0, stream>>>(cW1, Wt_c1, 128, 256);

    cnt_kernel<<<250, 256, 0, stream>>>(dstp, cnt);
    scan_kernel<<<1, 256, 0, stream>>>(cnt, rowptr, cursor);
    dis_kernel<<<8, 256, 0, stream>>>(cnt, dis);
    csr_fill_kernel<<<250, 256, 0, stream>>>(srcp, dstp, dis, cursor, esrc, enorm);

    gru_kernel<<<BN / 8, 128, 0, stream>>>(x, Wt4, W_ih, b_ih, b_hh, temporal);

    gcn_kernel<<<NN, 128, 0, stream>>>(temporal, rowptr, esrc, enorm, Wt_g1, gb1, lg1, lb1, sA);
    gcn_kernel<<<NN, 128, 0, stream>>>(sA, rowptr, esrc, enorm, Wt_g2, gb2, lg2, lb2, sB);

    classifier_kernel<<<BN / 8, 128, 0, stream>>>(temporal, sB, Wt_c1, cb1, cW2, cb2, out);
}

// Round 3
// 623.541 us; speedup vs baseline: 18.2970x; 18.2970x over previous
//
#include <hip/hip_runtime.h>
#include <math.h>

#define BB  4
#define NN  2000
#define TT  24
#define FIN 16
#define HH  128
#define EE  64000
#define CC  6
#define BN  (BB*NN)   // 8000

// ---------------- prep kernels ----------------
__global__ void transpose_kernel(const float* __restrict__ in, float* __restrict__ out,
                                 int R, int C) {
    int idx = blockIdx.x * 256 + threadIdx.x;
    if (idx < R * C) {
        int r = idx / C, c = idx - r * C;
        out[c * R + r] = in[idx];
    }
}

// W_hh[(g*128+j)][k]  ->  Wt4[(k>>2)][g][j][k&3]   (float4-loadable, coalesced over j)
__global__ void pack_whh_kernel(const float* __restrict__ W_hh, float* __restrict__ Wt4) {
    int idx = blockIdx.x * 256 + threadIdx.x;
    if (idx < 384 * 128) {
        int gi = idx >> 7;        // 0..383 (gate output row)
        int k  = idx & 127;       // 0..127 (input h index)
        int g  = gi >> 7;         // 0..2
        int j  = gi & 127;        // 0..127
        Wt4[(k >> 2) * 1536 + g * 512 + j * 4 + (k & 3)] = W_hh[idx];
    }
}

__global__ void cnt_kernel(const int* __restrict__ dst, int* __restrict__ cnt) {
    int e = blockIdx.x * 256 + threadIdx.x;
    if (e < EE) atomicAdd(&cnt[dst[e]], 1);
}

__global__ __launch_bounds__(256) void scan_kernel(const int* __restrict__ cnt,
                                                   int* __restrict__ rowptr,
                                                   int* __restrict__ cursor) {
    __shared__ int part[256];
    int tid = threadIdx.x;
    int base = tid * 8;
    int loc[8]; int s = 0;
    #pragma unroll
    for (int u = 0; u < 8; ++u) {
        int v = (base + u < NN) ? cnt[base + u] : 0;
        loc[u] = s; s += v;
    }
    part[tid] = s;
    __syncthreads();
    #pragma unroll
    for (int off = 1; off < 256; off <<= 1) {
        int add = (tid >= off) ? part[tid - off] : 0;
        __syncthreads();
        part[tid] += add;
        __syncthreads();
    }
    int offset = (tid > 0) ? part[tid - 1] : 0;
    #pragma unroll
    for (int u = 0; u < 8; ++u) {
        int idx = base + u;
        if (idx < NN) { rowptr[idx] = offset + loc[u]; cursor[idx] = offset + loc[u]; }
    }
    if (tid == 255) rowptr[NN] = part[255];
}

__global__ void dis_kernel(const int* __restrict__ cnt, float* __restrict__ dis) {
    int n = blockIdx.x * 256 + threadIdx.x;
    if (n < NN) dis[n] = rsqrtf(fmaxf((float)cnt[n], 1.0f));
}

__global__ void csr_fill_kernel(const int* __restrict__ src, const int* __restrict__ dst,
                                const float* __restrict__ dis, int* __restrict__ cursor,
                                int* __restrict__ esrc, float* __restrict__ enorm) {
    int e = blockIdx.x * 256 + threadIdx.x;
    if (e < EE) {
        int d = dst[e], s = src[e];
        int pos = atomicAdd(&cursor[d], 1);
        esrc[pos] = s;
        enorm[pos] = dis[s] * dis[d];
    }
}

// ---------------- GRU ----------------
// 8 sequences / block, 256 threads. j = tid&127 owns hidden unit j; half = tid>>7
// owns k in [half*64, half*64+64) of the hh-GEMV and f in [half*8, half*8+8) of the
// ih-GEMV. Partial gate sums reduced through LDS each t-step.
// NO explicit register double-buffering (R1 lesson: it spilled -> 12.6 GB scratch).
__global__ __launch_bounds__(256, 4) void gru_kernel(
    const float* __restrict__ x,       // [BN][TT][FIN]
    const float* __restrict__ Wt4,     // packed, see pack_whh_kernel
    const float* __restrict__ W_ih,    // [384][FIN]
    const float* __restrict__ b_ih, const float* __restrict__ b_hh,
    float* __restrict__ temporal)      // [BN][HH]
{
    const int tid  = threadIdx.x;
    const int j    = tid & 127;
    const int half = tid >> 7;
    const int seq0 = blockIdx.x * 8;

    __shared__ __align__(16) float xs[TT][8][FIN];  // 12 KB
    __shared__ __align__(16) float hs[HH][8];       // 4 KB
    __shared__ __align__(16) float part[32][128];   // 16 KB  [gate*8+s][j]

    const float* xg = x + (size_t)seq0 * TT * FIN;
    for (int i = tid; i < 8 * TT * FIN; i += 256) {
        int s = i / (TT * FIN);
        int rem = i - s * (TT * FIN);
        int t = rem / FIN;
        int f = rem - t * FIN;
        xs[t][s][f] = xg[i];
    }
    for (int i = tid; i < HH * 8; i += 256) ((float*)hs)[i] = 0.0f;

    // this half's 8 input features
    const int fbase = half * 8;
    float wir[8], wiz[8], win[8];
    #pragma unroll
    for (int u = 0; u < 8; ++u) {
        wir[u] = W_ih[(j      ) * FIN + fbase + u];
        wiz[u] = W_ih[(j + 128) * FIN + fbase + u];
        win[u] = W_ih[(j + 256) * FIN + fbase + u];
    }
    // biases only on half 0 (avoid double count)
    const float bra = (half == 0) ? (b_ih[j      ] + b_hh[j      ]) : 0.0f;
    const float bza = (half == 0) ? (b_ih[j + 128] + b_hh[j + 128]) : 0.0f;
    const float bha = (half == 0) ? b_hh[j + 256] : 0.0f;
    const float bia = (half == 0) ? b_ih[j + 256] : 0.0f;

    const float4* __restrict__ Wv = (const float4*)Wt4;  // [(k>>2)*384 + g*128 + j]
    const int c0 = half * 16;   // this half's chunk range (16 chunks = 64 k)

    __syncthreads();

    for (int t = 0; t < TT; ++t) {
        float ar[8], az[8], an[8], gn[8];
        #pragma unroll
        for (int s = 0; s < 8; ++s) { ar[s] = bra; az[s] = bza; an[s] = bha; gn[s] = bia; }

        // ih partial: this half's 8 features (r,z folded into ar/az; n-ih kept in gn)
        #pragma unroll
        for (int s = 0; s < 8; ++s) {
            float4 x0 = *(const float4*)&xs[t][s][fbase];
            float4 x1 = *(const float4*)&xs[t][s][fbase + 4];
            float xv[8] = {x0.x, x0.y, x0.z, x0.w, x1.x, x1.y, x1.z, x1.w};
            #pragma unroll
            for (int u = 0; u < 8; ++u) {
                ar[s] = fmaf(wir[u], xv[u], ar[s]);
                az[s] = fmaf(wiz[u], xv[u], az[s]);
                gn[s] = fmaf(win[u], xv[u], gn[s]);
            }
        }

        // hh partial: this half's 64 k (16 chunks of 4)
        #pragma unroll 2
        for (int c = 0; c < 16; ++c) {
            const int cc = c0 + c;
            const float4 wr = Wv[cc * 384 +       j];
            const float4 wz = Wv[cc * 384 + 128 + j];
            const float4 wn = Wv[cc * 384 + 256 + j];
            const int kb = cc * 4;
            #pragma unroll
            for (int q = 0; q < 4; ++q) {
                const float w_r = (q == 0) ? wr.x : (q == 1) ? wr.y : (q == 2) ? wr.z : wr.w;
                const float w_z = (q == 0) ? wz.x : (q == 1) ? wz.y : (q == 2) ? wz.z : wz.w;
                const float w_n = (q == 0) ? wn.x : (q == 1) ? wn.y : (q == 2) ? wn.z : wn.w;
                float4 h0 = *(const float4*)&hs[kb + q][0];
                float4 h1 = *(const float4*)&hs[kb + q][4];
                ar[0] = fmaf(w_r, h0.x, ar[0]); ar[1] = fmaf(w_r, h0.y, ar[1]);
                ar[2] = fmaf(w_r, h0.z, ar[2]); ar[3] = fmaf(w_r, h0.w, ar[3]);
                ar[4] = fmaf(w_r, h1.x, ar[4]); ar[5] = fmaf(w_r, h1.y, ar[5]);
                ar[6] = fmaf(w_r, h1.z, ar[6]); ar[7] = fmaf(w_r, h1.w, ar[7]);
                az[0] = fmaf(w_z, h0.x, az[0]); az[1] = fmaf(w_z, h0.y, az[1]);
                az[2] = fmaf(w_z, h0.z, az[2]); az[3] = fmaf(w_z, h0.w, az[3]);
                az[4] = fmaf(w_z, h1.x, az[4]); az[5] = fmaf(w_z, h1.y, az[5]);
                az[6] = fmaf(w_z, h1.z, az[6]); az[7] = fmaf(w_z, h1.w, az[7]);
                an[0] = fmaf(w_n, h0.x, an[0]); an[1] = fmaf(w_n, h0.y, an[1]);
                an[2] = fmaf(w_n, h0.z, an[2]); an[3] = fmaf(w_n, h0.w, an[3]);
                an[4] = fmaf(w_n, h1.x, an[4]); an[5] = fmaf(w_n, h1.y, an[5]);
                an[6] = fmaf(w_n, h1.z, an[6]); an[7] = fmaf(w_n, h1.w, an[7]);
            }
        }

        if (half == 1) {
            #pragma unroll
            for (int s = 0; s < 8; ++s) {
                part[s     ][j] = ar[s];
                part[8  + s][j] = az[s];
                part[16 + s][j] = an[s];
                part[24 + s][j] = gn[s];
            }
        }
        __syncthreads();
        if (half == 0) {
            #pragma unroll
            for (int s = 0; s < 8; ++s) {
                float vr  = ar[s] + part[s     ][j];
                float vz  = az[s] + part[8  + s][j];
                float vhn = an[s] + part[16 + s][j];
                float vin = gn[s] + part[24 + s][j];
                float r = 1.0f / (1.0f + __expf(-vr));
                float z = 1.0f / (1.0f + __expf(-vz));
                float u = vin + r * vhn;
                u = fminf(fmaxf(u, -20.0f), 20.0f);
                float e2 = __expf(2.0f * u);
                float nn = (e2 - 1.0f) / (e2 + 1.0f);
                hs[j][s] = (1.0f - z) * nn + z * hs[j][s];
            }
        }
        __syncthreads();
    }

    if (half == 0) {
        #pragma unroll
        for (int s = 0; s < 8; ++s)
            temporal[(size_t)(seq0 + s) * HH + j] = hs[j][s];
    }
}

// ---------------- fused GCN layer: gather + linear + LayerNorm + ReLU ----------------
__global__ __launch_bounds__(128) void gcn_kernel(
    const float* __restrict__ xin,     // [BB][NN][HH]
    const int* __restrict__ rowptr,    // [NN+1]
    const int* __restrict__ esrc,      // edges sorted by dst
    const float* __restrict__ enorm,
    const float* __restrict__ Wt,      // [HH][HH]  Wt[k][j] = W[j][k]
    const float* __restrict__ bias,
    const float* __restrict__ gma, const float* __restrict__ bta,
    float* __restrict__ out)           // [BB][NN][HH]
{
    const int n = blockIdx.x;
    const int j = threadIdx.x;
    const int beg = rowptr[n], end = rowptr[n + 1];

    float a0 = 0.f, a1 = 0.f, a2 = 0.f, a3 = 0.f;
    int e = beg;
    for (; e + 1 < end; e += 2) {
        int   s0 = esrc[e],   s1 = esrc[e + 1];
        float m0 = enorm[e],  m1 = enorm[e + 1];
        const float* p0 = xin + (size_t)s0 * HH + j;
        const float* p1 = xin + (size_t)s1 * HH + j;
        float v00 = p0[0], v01 = p0[NN*HH], v02 = p0[2*NN*HH], v03 = p0[3*NN*HH];
        float v10 = p1[0], v11 = p1[NN*HH], v12 = p1[2*NN*HH], v13 = p1[3*NN*HH];
        a0 = fmaf(m0, v00, a0); a1 = fmaf(m0, v01, a1);
        a2 = fmaf(m0, v02, a2); a3 = fmaf(m0, v03, a3);
        a0 = fmaf(m1, v10, a0); a1 = fmaf(m1, v11, a1);
        a2 = fmaf(m1, v12, a2); a3 = fmaf(m1, v13, a3);
    }
    if (e < end) {
        int s0 = esrc[e]; float m0 = enorm[e];
        const float* p0 = xin + (size_t)s0 * HH + j;
        a0 = fmaf(m0, p0[0],       a0); a1 = fmaf(m0, p0[NN*HH],   a1);
        a2 = fmaf(m0, p0[2*NN*HH], a2); a3 = fmaf(m0, p0[3*NN*HH], a3);
    }

    __shared__ __align__(16) float agg[BB][HH];
    agg[0][j] = a0; agg[1][j] = a1; agg[2][j] = a2; agg[3][j] = a3;
    __syncthreads();

    const float bj = bias[j];
    float c0 = bj, c1 = bj, c2 = bj, c3 = bj;
    #pragma unroll 4
    for (int k = 0; k < HH; ++k) {
        float w = Wt[k * HH + j];
        c0 = fmaf(w, agg[0][k], c0);
        c1 = fmaf(w, agg[1][k], c1);
        c2 = fmaf(w, agg[2][k], c2);
        c3 = fmaf(w, agg[3][k], c3);
    }

    const int lane = j & 63, wid = j >> 6;
    __shared__ float red[2][BB][2];
    const float gj = gma[j], btj = bta[j];

#define LNRED(cv, b) do { \
        float s1 = (cv), s2 = (cv) * (cv); \
        for (int off = 32; off >= 1; off >>= 1) { s1 += __shfl_down(s1, off); s2 += __shfl_down(s2, off); } \
        if (lane == 0) { red[wid][b][0] = s1; red[wid][b][1] = s2; } \
    } while (0)
    LNRED(c0, 0); LNRED(c1, 1); LNRED(c2, 2); LNRED(c3, 3);
    __syncthreads();

#define LNOUT(cv, b) do { \
        float s1 = red[0][b][0] + red[1][b][0]; \
        float s2 = red[0][b][1] + red[1][b][1]; \
        float mu = s1 * (1.0f / HH); \
        float var = s2 * (1.0f / HH) - mu * mu; \
        float y = ((cv) - mu) * rsqrtf(var + 1e-5f) * gj + btj; \
        out[((size_t)(b) * NN + n) * HH + j] = fmaxf(y, 0.0f); \
    } while (0)
    LNOUT(c0, 0); LNOUT(c1, 1); LNOUT(c2, 2); LNOUT(c3, 3);
#undef LNRED
#undef LNOUT
}

// ---------------- classifier (fused 2-layer MLP) ----------------
__global__ __launch_bounds__(128) void classifier_kernel(
    const float* __restrict__ tin,   // temporal [BN][HH]
    const float* __restrict__ sin_,  // spatial  [BN][HH]
    const float* __restrict__ Wt1,   // [2*HH][HH]
    const float* __restrict__ b1,
    const float* __restrict__ W2,    // [CC][HH]
    const float* __restrict__ b2,
    float* __restrict__ out)         // [BN][CC]
{
    const int j = threadIdx.x;
    const int r0 = blockIdx.x * 8;
    __shared__ __align__(16) float tb[HH][8];
    __shared__ __align__(16) float sb[HH][8];
    __shared__ __align__(16) float h1[HH][8];
    for (int i = j; i < 8 * HH; i += 128) {
        int r = i >> 7, k = i & 127;
        tb[k][r] = tin [(size_t)(r0 + r) * HH + k];
        sb[k][r] = sin_[(size_t)(r0 + r) * HH + k];
    }
    __syncthreads();

    float acc[8];
    float bj = b1[j];
    #pragma unroll
    for (int r = 0; r < 8; ++r) acc[r] = bj;
    #pragma unroll 2
    for (int k = 0; k < HH; ++k) {
        float w = Wt1[k * HH + j];
        float4 a  = *(const float4*)&tb[k][0];
        float4 b4 = *(const float4*)&tb[k][4];
        acc[0] = fmaf(w, a.x,  acc[0]); acc[1] = fmaf(w, a.y,  acc[1]);
        acc[2] = fmaf(w, a.z,  acc[2]); acc[3] = fmaf(w, a.w,  acc[3]);
        acc[4] = fmaf(w, b4.x, acc[4]); acc[5] = fmaf(w, b4.y, acc[5]);
        acc[6] = fmaf(w, b4.z, acc[6]); acc[7] = fmaf(w, b4.w, acc[7]);
    }
    #pragma unroll 2
    for (int k = 0; k < HH; ++k) {
        float w = Wt1[(HH + k) * HH + j];
        float4 a  = *(const float4*)&sb[k][0];
        float4 b4 = *(const float4*)&sb[k][4];
        acc[0] = fmaf(w, a.x,  acc[0]); acc[1] = fmaf(w, a.y,  acc[1]);
        acc[2] = fmaf(w, a.z,  acc[2]); acc[3] = fmaf(w, a.w,  acc[3]);
        acc[4] = fmaf(w, b4.x, acc[4]); acc[5] = fmaf(w, b4.y, acc[5]);
        acc[6] = fmaf(w, b4.z, acc[6]); acc[7] = fmaf(w, b4.w, acc[7]);
    }
    #pragma unroll
    for (int r = 0; r < 8; ++r) h1[j][r] = fmaxf(acc[r], 0.0f);
    __syncthreads();

    if (j < 8 * CC) {
        int r = j / CC, c = j - r * CC;
        float a = b2[c];
        for (int k = 0; k < HH; ++k) a = fmaf(W2[c * HH + k], h1[k][r], a);
        out[(size_t)(r0 + r) * CC + c] = a;
    }
}

// ---------------- launch ----------------
extern "C" void kernel_launch(void* const* d_in, const int* in_sizes, int n_in,
                              void* d_out, int out_size, void* d_ws, size_t ws_size,
                              hipStream_t stream) {
    const float* x    = (const float*)d_in[0];
    const int*   ei   = (const int*)  d_in[1];
    const float* W_ih = (const float*)d_in[2];
    const float* W_hh = (const float*)d_in[3];
    const float* b_ih = (const float*)d_in[4];
    const float* b_hh = (const float*)d_in[5];
    const float* gW1  = (const float*)d_in[6];
    const float* gb1  = (const float*)d_in[7];
    const float* gW2  = (const float*)d_in[8];
    const float* gb2  = (const float*)d_in[9];
    const float* lg1  = (const float*)d_in[10];
    const float* lb1  = (const float*)d_in[11];
    const float* lg2  = (const float*)d_in[12];
    const float* lb2  = (const float*)d_in[13];
    const float* cW1  = (const float*)d_in[14];
    const float* cb1  = (const float*)d_in[15];
    const float* cW2  = (const float*)d_in[16];
    const float* cb2  = (const float*)d_in[17];
    float* out = (float*)d_out;

    float* ws = (float*)d_ws;
    float* Wt4   = ws;  ws += 384 * 128;
    float* Wt_g1 = ws;  ws += 128 * 128;
    float* Wt_g2 = ws;  ws += 128 * 128;
    float* Wt_c1 = ws;  ws += 256 * 128;
    float* dis   = ws;  ws += 2048;
    float* enorm = ws;  ws += EE;
    float* temporal = ws; ws += (size_t)BN * HH;
    float* sA    = ws;  ws += (size_t)BN * HH;
    float* sB    = ws;  ws += (size_t)BN * HH;
    int* ip      = (int*)ws;
    int* cnt     = ip;  ip += 2048;
    int* rowptr  = ip;  ip += 2080;
    int* cursor  = ip;  ip += 2048;
    int* esrc    = ip;  ip += EE;

    const int* srcp = ei;
    const int* dstp = ei + EE;

    hipMemsetAsync(cnt, 0, 2048 * sizeof(int), stream);

    pack_whh_kernel<<<192, 256, 0, stream>>>(W_hh, Wt4);
    transpose_kernel<<<64, 256, 0, stream>>>(gW1, Wt_g1, 128, 128);
    transpose_kernel<<<64, 256, 0, stream>>>(gW2, Wt_g2, 128, 128);
    transpose_kernel<<<128, 256, 0, stream>>>(cW1, Wt_c1, 128, 256);

    cnt_kernel<<<250, 256, 0, stream>>>(dstp, cnt);
    scan_kernel<<<1, 256, 0, stream>>>(cnt, rowptr, cursor);
    dis_kernel<<<8, 256, 0, stream>>>(cnt, dis);
    csr_fill_kernel<<<250, 256, 0, stream>>>(srcp, dstp, dis, cursor, esrc, enorm);

    gru_kernel<<<BN / 8, 256, 0, stream>>>(x, Wt4, W_ih, b_ih, b_hh, temporal);

    gcn_kernel<<<NN, 128, 0, stream>>>(temporal, rowptr, esrc, enorm, Wt_g1, gb1, lg1, lb1, sA);
    gcn_kernel<<<NN, 128, 0, stream>>>(sA, rowptr, esrc, enorm, Wt_g2, gb2, lg2, lb2, sB);

    classifier_kernel<<<BN / 8, 128, 0, stream>>>(temporal, sB, Wt_c1, cb1, cW2, cb2, out);
}

// Round 4
// 482.832 us; speedup vs baseline: 23.6292x; 1.2914x over previous
//
#include <hip/hip_runtime.h>
#include <math.h>

#define BB  4
#define NN  2000
#define TT  24
#define FIN 16
#define HH  128
#define EE  64000
#define CC  6
#define BN  (BB*NN)   // 8000

// ---------------- prep kernels ----------------
__global__ void transpose_kernel(const float* __restrict__ in, float* __restrict__ out,
                                 int R, int C) {
    int idx = blockIdx.x * 256 + threadIdx.x;
    if (idx < R * C) {
        int r = idx / C, c = idx - r * C;
        out[c * R + r] = in[idx];
    }
}

// W_hh[(g*128+j)][k]  ->  Wt4[(k>>2)][g][j][k&3]   (float4-loadable, coalesced over j)
__global__ void pack_whh_kernel(const float* __restrict__ W_hh, float* __restrict__ Wt4) {
    int idx = blockIdx.x * 256 + threadIdx.x;
    if (idx < 384 * 128) {
        int gi = idx >> 7;        // 0..383 (gate output row)
        int k  = idx & 127;       // 0..127 (input h index)
        int g  = gi >> 7;         // 0..2
        int j  = gi & 127;        // 0..127
        Wt4[(k >> 2) * 1536 + g * 512 + j * 4 + (k & 3)] = W_hh[idx];
    }
}

__global__ void cnt_kernel(const int* __restrict__ dst, int* __restrict__ cnt) {
    int e = blockIdx.x * 256 + threadIdx.x;
    if (e < EE) atomicAdd(&cnt[dst[e]], 1);
}

__global__ __launch_bounds__(256) void scan_kernel(const int* __restrict__ cnt,
                                                   int* __restrict__ rowptr,
                                                   int* __restrict__ cursor) {
    __shared__ int part[256];
    int tid = threadIdx.x;
    int base = tid * 8;
    int loc[8]; int s = 0;
    #pragma unroll
    for (int u = 0; u < 8; ++u) {
        int v = (base + u < NN) ? cnt[base + u] : 0;
        loc[u] = s; s += v;
    }
    part[tid] = s;
    __syncthreads();
    #pragma unroll
    for (int off = 1; off < 256; off <<= 1) {
        int add = (tid >= off) ? part[tid - off] : 0;
        __syncthreads();
        part[tid] += add;
        __syncthreads();
    }
    int offset = (tid > 0) ? part[tid - 1] : 0;
    #pragma unroll
    for (int u = 0; u < 8; ++u) {
        int idx = base + u;
        if (idx < NN) { rowptr[idx] = offset + loc[u]; cursor[idx] = offset + loc[u]; }
    }
    if (tid == 255) rowptr[NN] = part[255];
}

__global__ void dis_kernel(const int* __restrict__ cnt, float* __restrict__ dis) {
    int n = blockIdx.x * 256 + threadIdx.x;
    if (n < NN) dis[n] = rsqrtf(fmaxf((float)cnt[n], 1.0f));
}

__global__ void csr_fill_kernel(const int* __restrict__ src, const int* __restrict__ dst,
                                const float* __restrict__ dis, int* __restrict__ cursor,
                                int* __restrict__ esrc, float* __restrict__ enorm) {
    int e = blockIdx.x * 256 + threadIdx.x;
    if (e < EE) {
        int d = dst[e], s = src[e];
        int pos = atomicAdd(&cursor[d], 1);
        esrc[pos] = s;
        enorm[pos] = dis[s] * dis[d];
    }
}

// ---------------- GRU ----------------
// 8 sequences / block, 256 threads. j = tid&127 owns hidden unit j; half = tid>>7
// owns k in [half*64, half*64+64) of the hh-GEMV and f in [half*8, half*8+8) of the
// ih-GEMV. Partial gate sums reduced through LDS each t-step.
// NO min-occupancy hint: R2's (128,2)=64-cap and R3's (256,4) both forced VGPR caps
// below the ~91-reg live set -> 0.5-12 GB scratch spill. Live set needs ~96-128.
__global__ __launch_bounds__(256) void gru_kernel(
    const float* __restrict__ x,       // [BN][TT][FIN]
    const float* __restrict__ Wt4,     // packed, see pack_whh_kernel
    const float* __restrict__ W_ih,    // [384][FIN]
    const float* __restrict__ b_ih, const float* __restrict__ b_hh,
    float* __restrict__ temporal)      // [BN][HH]
{
    const int tid  = threadIdx.x;
    const int j    = tid & 127;
    const int half = tid >> 7;
    const int seq0 = blockIdx.x * 8;

    __shared__ __align__(16) float xs[TT][8][FIN];  // 12 KB
    __shared__ __align__(16) float hs[HH][8];       // 4 KB
    __shared__ __align__(16) float part[32][128];   // 16 KB  [gate*8+s][j]

    const float* xg = x + (size_t)seq0 * TT * FIN;
    for (int i = tid; i < 8 * TT * FIN; i += 256) {
        int s = i / (TT * FIN);
        int rem = i - s * (TT * FIN);
        int t = rem / FIN;
        int f = rem - t * FIN;
        xs[t][s][f] = xg[i];
    }
    for (int i = tid; i < HH * 8; i += 256) ((float*)hs)[i] = 0.0f;

    // this half's 8 input features
    const int fbase = half * 8;
    float wir[8], wiz[8], win[8];
    #pragma unroll
    for (int u = 0; u < 8; ++u) {
        wir[u] = W_ih[(j      ) * FIN + fbase + u];
        wiz[u] = W_ih[(j + 128) * FIN + fbase + u];
        win[u] = W_ih[(j + 256) * FIN + fbase + u];
    }
    // biases only on half 0 (avoid double count)
    const float bra = (half == 0) ? (b_ih[j      ] + b_hh[j      ]) : 0.0f;
    const float bza = (half == 0) ? (b_ih[j + 128] + b_hh[j + 128]) : 0.0f;
    const float bha = (half == 0) ? b_hh[j + 256] : 0.0f;
    const float bia = (half == 0) ? b_ih[j + 256] : 0.0f;

    const float4* __restrict__ Wv = (const float4*)Wt4;  // [(k>>2)*384 + g*128 + j]
    const int c0 = half * 16;   // this half's chunk range (16 chunks = 64 k)

    __syncthreads();

    for (int t = 0; t < TT; ++t) {
        float ar[8], az[8], an[8], gn[8];
        #pragma unroll
        for (int s = 0; s < 8; ++s) { ar[s] = bra; az[s] = bza; an[s] = bha; gn[s] = bia; }

        // ih partial: this half's 8 features (r,z folded into ar/az; n-ih kept in gn)
        #pragma unroll
        for (int s = 0; s < 8; ++s) {
            float4 x0 = *(const float4*)&xs[t][s][fbase];
            float4 x1 = *(const float4*)&xs[t][s][fbase + 4];
            float xv[8] = {x0.x, x0.y, x0.z, x0.w, x1.x, x1.y, x1.z, x1.w};
            #pragma unroll
            for (int u = 0; u < 8; ++u) {
                ar[s] = fmaf(wir[u], xv[u], ar[s]);
                az[s] = fmaf(wiz[u], xv[u], az[s]);
                gn[s] = fmaf(win[u], xv[u], gn[s]);
            }
        }

        // hh partial: this half's 64 k (16 chunks of 4)
        #pragma unroll 2
        for (int c = 0; c < 16; ++c) {
            const int cc = c0 + c;
            const float4 wr = Wv[cc * 384 +       j];
            const float4 wz = Wv[cc * 384 + 128 + j];
            const float4 wn = Wv[cc * 384 + 256 + j];
            const int kb = cc * 4;
            #pragma unroll
            for (int q = 0; q < 4; ++q) {
                const float w_r = (q == 0) ? wr.x : (q == 1) ? wr.y : (q == 2) ? wr.z : wr.w;
                const float w_z = (q == 0) ? wz.x : (q == 1) ? wz.y : (q == 2) ? wz.z : wz.w;
                const float w_n = (q == 0) ? wn.x : (q == 1) ? wn.y : (q == 2) ? wn.z : wn.w;
                float4 h0 = *(const float4*)&hs[kb + q][0];
                float4 h1 = *(const float4*)&hs[kb + q][4];
                ar[0] = fmaf(w_r, h0.x, ar[0]); ar[1] = fmaf(w_r, h0.y, ar[1]);
                ar[2] = fmaf(w_r, h0.z, ar[2]); ar[3] = fmaf(w_r, h0.w, ar[3]);
                ar[4] = fmaf(w_r, h1.x, ar[4]); ar[5] = fmaf(w_r, h1.y, ar[5]);
                ar[6] = fmaf(w_r, h1.z, ar[6]); ar[7] = fmaf(w_r, h1.w, ar[7]);
                az[0] = fmaf(w_z, h0.x, az[0]); az[1] = fmaf(w_z, h0.y, az[1]);
                az[2] = fmaf(w_z, h0.z, az[2]); az[3] = fmaf(w_z, h0.w, az[3]);
                az[4] = fmaf(w_z, h1.x, az[4]); az[5] = fmaf(w_z, h1.y, az[5]);
                az[6] = fmaf(w_z, h1.z, az[6]); az[7] = fmaf(w_z, h1.w, az[7]);
                an[0] = fmaf(w_n, h0.x, an[0]); an[1] = fmaf(w_n, h0.y, an[1]);
                an[2] = fmaf(w_n, h0.z, an[2]); an[3] = fmaf(w_n, h0.w, an[3]);
                an[4] = fmaf(w_n, h1.x, an[4]); an[5] = fmaf(w_n, h1.y, an[5]);
                an[6] = fmaf(w_n, h1.z, an[6]); an[7] = fmaf(w_n, h1.w, an[7]);
            }
        }

        if (half == 1) {
            #pragma unroll
            for (int s = 0; s < 8; ++s) {
                part[s     ][j] = ar[s];
                part[8  + s][j] = az[s];
                part[16 + s][j] = an[s];
                part[24 + s][j] = gn[s];
            }
        }
        __syncthreads();
        if (half == 0) {
            #pragma unroll
            for (int s = 0; s < 8; ++s) {
                float vr  = ar[s] + part[s     ][j];
                float vz  = az[s] + part[8  + s][j];
                float vhn = an[s] + part[16 + s][j];
                float vin = gn[s] + part[24 + s][j];
                float r = 1.0f / (1.0f + __expf(-vr));
                float z = 1.0f / (1.0f + __expf(-vz));
                float u = vin + r * vhn;
                u = fminf(fmaxf(u, -20.0f), 20.0f);
                float e2 = __expf(2.0f * u);
                float nn = (e2 - 1.0f) / (e2 + 1.0f);
                hs[j][s] = (1.0f - z) * nn + z * hs[j][s];
            }
        }
        __syncthreads();
    }

    if (half == 0) {
        #pragma unroll
        for (int s = 0; s < 8; ++s)
            temporal[(size_t)(seq0 + s) * HH + j] = hs[j][s];
    }
}

// ---------------- fused GCN layer: gather + linear + LayerNorm + ReLU ----------------
__global__ __launch_bounds__(128) void gcn_kernel(
    const float* __restrict__ xin,     // [BB][NN][HH]
    const int* __restrict__ rowptr,    // [NN+1]
    const int* __restrict__ esrc,      // edges sorted by dst
    const float* __restrict__ enorm,
    const float* __restrict__ Wt,      // [HH][HH]  Wt[k][j] = W[j][k]
    const float* __restrict__ bias,
    const float* __restrict__ gma, const float* __restrict__ bta,
    float* __restrict__ out)           // [BB][NN][HH]
{
    const int n = blockIdx.x;
    const int j = threadIdx.x;
    const int beg = rowptr[n], end = rowptr[n + 1];

    float a0 = 0.f, a1 = 0.f, a2 = 0.f, a3 = 0.f;
    int e = beg;
    for (; e + 1 < end; e += 2) {
        int   s0 = esrc[e],   s1 = esrc[e + 1];
        float m0 = enorm[e],  m1 = enorm[e + 1];
        const float* p0 = xin + (size_t)s0 * HH + j;
        const float* p1 = xin + (size_t)s1 * HH + j;
        float v00 = p0[0], v01 = p0[NN*HH], v02 = p0[2*NN*HH], v03 = p0[3*NN*HH];
        float v10 = p1[0], v11 = p1[NN*HH], v12 = p1[2*NN*HH], v13 = p1[3*NN*HH];
        a0 = fmaf(m0, v00, a0); a1 = fmaf(m0, v01, a1);
        a2 = fmaf(m0, v02, a2); a3 = fmaf(m0, v03, a3);
        a0 = fmaf(m1, v10, a0); a1 = fmaf(m1, v11, a1);
        a2 = fmaf(m1, v12, a2); a3 = fmaf(m1, v13, a3);
    }
    if (e < end) {
        int s0 = esrc[e]; float m0 = enorm[e];
        const float* p0 = xin + (size_t)s0 * HH + j;
        a0 = fmaf(m0, p0[0],       a0); a1 = fmaf(m0, p0[NN*HH],   a1);
        a2 = fmaf(m0, p0[2*NN*HH], a2); a3 = fmaf(m0, p0[3*NN*HH], a3);
    }

    __shared__ __align__(16) float agg[BB][HH];
    agg[0][j] = a0; agg[1][j] = a1; agg[2][j] = a2; agg[3][j] = a3;
    __syncthreads();

    const float bj = bias[j];
    float c0 = bj, c1 = bj, c2 = bj, c3 = bj;
    #pragma unroll 4
    for (int k = 0; k < HH; ++k) {
        float w = Wt[k * HH + j];
        c0 = fmaf(w, agg[0][k], c0);
        c1 = fmaf(w, agg[1][k], c1);
        c2 = fmaf(w, agg[2][k], c2);
        c3 = fmaf(w, agg[3][k], c3);
    }

    const int lane = j & 63, wid = j >> 6;
    __shared__ float red[2][BB][2];
    const float gj = gma[j], btj = bta[j];

#define LNRED(cv, b) do { \
        float s1 = (cv), s2 = (cv) * (cv); \
        for (int off = 32; off >= 1; off >>= 1) { s1 += __shfl_down(s1, off); s2 += __shfl_down(s2, off); } \
        if (lane == 0) { red[wid][b][0] = s1; red[wid][b][1] = s2; } \
    } while (0)
    LNRED(c0, 0); LNRED(c1, 1); LNRED(c2, 2); LNRED(c3, 3);
    __syncthreads();

#define LNOUT(cv, b) do { \
        float s1 = red[0][b][0] + red[1][b][0]; \
        float s2 = red[0][b][1] + red[1][b][1]; \
        float mu = s1 * (1.0f / HH); \
        float var = s2 * (1.0f / HH) - mu * mu; \
        float y = ((cv) - mu) * rsqrtf(var + 1e-5f) * gj + btj; \
        out[((size_t)(b) * NN + n) * HH + j] = fmaxf(y, 0.0f); \
    } while (0)
    LNOUT(c0, 0); LNOUT(c1, 1); LNOUT(c2, 2); LNOUT(c3, 3);
#undef LNRED
#undef LNOUT
}

// ---------------- classifier (fused 2-layer MLP) ----------------
__global__ __launch_bounds__(128) void classifier_kernel(
    const float* __restrict__ tin,   // temporal [BN][HH]
    const float* __restrict__ sin_,  // spatial  [BN][HH]
    const float* __restrict__ Wt1,   // [2*HH][HH]
    const float* __restrict__ b1,
    const float* __restrict__ W2,    // [CC][HH]
    const float* __restrict__ b2,
    float* __restrict__ out)         // [BN][CC]
{
    const int j = threadIdx.x;
    const int r0 = blockIdx.x * 8;
    __shared__ __align__(16) float tb[HH][8];
    __shared__ __align__(16) float sb[HH][8];
    __shared__ __align__(16) float h1[HH][8];
    for (int i = j; i < 8 * HH; i += 128) {
        int r = i >> 7, k = i & 127;
        tb[k][r] = tin [(size_t)(r0 + r) * HH + k];
        sb[k][r] = sin_[(size_t)(r0 + r) * HH + k];
    }
    __syncthreads();

    float acc[8];
    float bj = b1[j];
    #pragma unroll
    for (int r = 0; r < 8; ++r) acc[r] = bj;
    #pragma unroll 2
    for (int k = 0; k < HH; ++k) {
        float w = Wt1[k * HH + j];
        float4 a  = *(const float4*)&tb[k][0];
        float4 b4 = *(const float4*)&tb[k][4];
        acc[0] = fmaf(w, a.x,  acc[0]); acc[1] = fmaf(w, a.y,  acc[1]);
        acc[2] = fmaf(w, a.z,  acc[2]); acc[3] = fmaf(w, a.w,  acc[3]);
        acc[4] = fmaf(w, b4.x, acc[4]); acc[5] = fmaf(w, b4.y, acc[5]);
        acc[6] = fmaf(w, b4.z, acc[6]); acc[7] = fmaf(w, b4.w, acc[7]);
    }
    #pragma unroll 2
    for (int k = 0; k < HH; ++k) {
        float w = Wt1[(HH + k) * HH + j];
        float4 a  = *(const float4*)&sb[k][0];
        float4 b4 = *(const float4*)&sb[k][4];
        acc[0] = fmaf(w, a.x,  acc[0]); acc[1] = fmaf(w, a.y,  acc[1]);
        acc[2] = fmaf(w, a.z,  acc[2]); acc[3] = fmaf(w, a.w,  acc[3]);
        acc[4] = fmaf(w, b4.x, acc[4]); acc[5] = fmaf(w, b4.y, acc[5]);
        acc[6] = fmaf(w, b4.z, acc[6]); acc[7] = fmaf(w, b4.w, acc[7]);
    }
    #pragma unroll
    for (int r = 0; r < 8; ++r) h1[j][r] = fmaxf(acc[r], 0.0f);
    __syncthreads();

    if (j < 8 * CC) {
        int r = j / CC, c = j - r * CC;
        float a = b2[c];
        for (int k = 0; k < HH; ++k) a = fmaf(W2[c * HH + k], h1[k][r], a);
        out[(size_t)(r0 + r) * CC + c] = a;
    }
}

// ---------------- launch ----------------
extern "C" void kernel_launch(void* const* d_in, const int* in_sizes, int n_in,
                              void* d_out, int out_size, void* d_ws, size_t ws_size,
                              hipStream_t stream) {
    const float* x    = (const float*)d_in[0];
    const int*   ei   = (const int*)  d_in[1];
    const float* W_ih = (const float*)d_in[2];
    const float* W_hh = (const float*)d_in[3];
    const float* b_ih = (const float*)d_in[4];
    const float* b_hh = (const float*)d_in[5];
    const float* gW1  = (const float*)d_in[6];
    const float* gb1  = (const float*)d_in[7];
    const float* gW2  = (const float*)d_in[8];
    const float* gb2  = (const float*)d_in[9];
    const float* lg1  = (const float*)d_in[10];
    const float* lb1  = (const float*)d_in[11];
    const float* lg2  = (const float*)d_in[12];
    const float* lb2  = (const float*)d_in[13];
    const float* cW1  = (const float*)d_in[14];
    const float* cb1  = (const float*)d_in[15];
    const float* cW2  = (const float*)d_in[16];
    const float* cb2  = (const float*)d_in[17];
    float* out = (float*)d_out;

    float* ws = (float*)d_ws;
    float* Wt4   = ws;  ws += 384 * 128;
    float* Wt_g1 = ws;  ws += 128 * 128;
    float* Wt_g2 = ws;  ws += 128 * 128;
    float* Wt_c1 = ws;  ws += 256 * 128;
    float* dis   = ws;  ws += 2048;
    float* enorm = ws;  ws += EE;
    float* temporal = ws; ws += (size_t)BN * HH;
    float* sA    = ws;  ws += (size_t)BN * HH;
    float* sB    = ws;  ws += (size_t)BN * HH;
    int* ip      = (int*)ws;
    int* cnt     = ip;  ip += 2048;
    int* rowptr  = ip;  ip += 2080;
    int* cursor  = ip;  ip += 2048;
    int* esrc    = ip;  ip += EE;

    const int* srcp = ei;
    const int* dstp = ei + EE;

    hipMemsetAsync(cnt, 0, 2048 * sizeof(int), stream);

    pack_whh_kernel<<<192, 256, 0, stream>>>(W_hh, Wt4);
    transpose_kernel<<<64, 256, 0, stream>>>(gW1, Wt_g1, 128, 128);
    transpose_kernel<<<64, 256, 0, stream>>>(gW2, Wt_g2, 128, 128);
    transpose_kernel<<<128, 256, 0, stream>>>(cW1, Wt_c1, 128, 256);

    cnt_kernel<<<250, 256, 0, stream>>>(dstp, cnt);
    scan_kernel<<<1, 256, 0, stream>>>(cnt, rowptr, cursor);
    dis_kernel<<<8, 256, 0, stream>>>(cnt, dis);
    csr_fill_kernel<<<250, 256, 0, stream>>>(srcp, dstp, dis, cursor, esrc, enorm);

    gru_kernel<<<BN / 8, 256, 0, stream>>>(x, Wt4, W_ih, b_ih, b_hh, temporal);

    gcn_kernel<<<NN, 128, 0, stream>>>(temporal, rowptr, esrc, enorm, Wt_g1, gb1, lg1, lb1, sA);
    gcn_kernel<<<NN, 128, 0, stream>>>(sA, rowptr, esrc, enorm, Wt_g2, gb2, lg2, lb2, sB);

    classifier_kernel<<<BN / 8, 128, 0, stream>>>(temporal, sB, Wt_c1, cb1, cW2, cb2, out);
}

// Round 5
// 234.048 us; speedup vs baseline: 48.7462x; 2.0630x over previous
//
#include <hip/hip_runtime.h>
#include <math.h>

#define BB  4
#define NN  2000
#define TT  24
#define FIN 16
#define HH  128
#define EE  64000
#define CC  6
#define BN  (BB*NN)   // 8000

typedef __attribute__((ext_vector_type(8))) short bf16x8;
typedef __attribute__((ext_vector_type(4))) float f32x4;

__device__ __forceinline__ short f2bf(float v) {
    unsigned u = __float_as_uint(v);
    unsigned r = (u + 0x7fffu + ((u >> 16) & 1u)) >> 16;
    return (short)r;
}
__device__ __forceinline__ float bf2f(short b) {
    return __uint_as_float(((unsigned)(unsigned short)b) << 16);
}

// ---------------- prep kernels ----------------
__global__ void transpose_kernel(const float* __restrict__ in, float* __restrict__ out,
                                 int R, int C) {
    int idx = blockIdx.x * 256 + threadIdx.x;
    if (idx < R * C) {
        int r = idx / C, c = idx - r * C;
        out[c * R + r] = in[idx];
    }
}

__global__ void cnt_kernel(const int* __restrict__ dst, int* __restrict__ cnt) {
    int e = blockIdx.x * 256 + threadIdx.x;
    if (e < EE) atomicAdd(&cnt[dst[e]], 1);
}

__global__ __launch_bounds__(256) void scan_kernel(const int* __restrict__ cnt,
                                                   int* __restrict__ rowptr,
                                                   int* __restrict__ cursor) {
    __shared__ int part[256];
    int tid = threadIdx.x;
    int base = tid * 8;
    int loc[8]; int s = 0;
    #pragma unroll
    for (int u = 0; u < 8; ++u) {
        int v = (base + u < NN) ? cnt[base + u] : 0;
        loc[u] = s; s += v;
    }
    part[tid] = s;
    __syncthreads();
    #pragma unroll
    for (int off = 1; off < 256; off <<= 1) {
        int add = (tid >= off) ? part[tid - off] : 0;
        __syncthreads();
        part[tid] += add;
        __syncthreads();
    }
    int offset = (tid > 0) ? part[tid - 1] : 0;
    #pragma unroll
    for (int u = 0; u < 8; ++u) {
        int idx = base + u;
        if (idx < NN) { rowptr[idx] = offset + loc[u]; cursor[idx] = offset + loc[u]; }
    }
    if (tid == 255) rowptr[NN] = part[255];
}

__global__ void dis_kernel(const int* __restrict__ cnt, float* __restrict__ dis) {
    int n = blockIdx.x * 256 + threadIdx.x;
    if (n < NN) dis[n] = rsqrtf(fmaxf((float)cnt[n], 1.0f));
}

__global__ void csr_fill_kernel(const int* __restrict__ src, const int* __restrict__ dst,
                                const float* __restrict__ dis, int* __restrict__ cursor,
                                int* __restrict__ esrc, float* __restrict__ enorm) {
    int e = blockIdx.x * 256 + threadIdx.x;
    if (e < EE) {
        int d = dst[e], s = src[e];
        int pos = atomicAdd(&cursor[d], 1);
        esrc[pos] = s;
        enorm[pos] = dis[s] * dis[d];
    }
}

// ---------------- GRU via MFMA ----------------
// Block = 512 threads = 8 waves, owns 32 sequences for all 24 steps (no grid sync).
// Wave w owns gate-output cols [w*48, w*48+48) = n-tiles w*3..w*3+2 (16 cols each,
// tiles never straddle a gate boundary since 128/16=8 tiles per gate).
// W_hh held in registers as bf16 hi/lo B-fragments (split: w = hi + lo, 3-term MFMA
// hi*hi + hi*lo + lo*hi gives ~fp32 accuracy). H state in LDS packed (hi|lo) per dword.
// Biases folded via a k==16 "ones" column in the x-fragment (except bhn, kept in regs
// because n = tanh(inn + bin + r*(hn + bhn)) needs it inside the r*() term).
// Fragment k-map: SAME function of (i, lane>>4) used for A and B everywhere, so any
// k-permutation in the HW operand layout cancels in the contraction.
// C/D layout (verified): col = lane&15, row = (lane>>4)*4 + reg.
#define HP 132   // H lds stride (dwords): 4*row%32 -> 2-way bank alias (free)
#define GS 532   // G lds stride (floats): 16B-aligned rows, 2-way alias on C-writes

__global__ __launch_bounds__(512) void gru_mfma_kernel(
    const float* __restrict__ x,       // [BN][TT][FIN]
    const float* __restrict__ W_hh,    // [384][128]
    const float* __restrict__ W_ih,    // [384][16]
    const float* __restrict__ b_ih, const float* __restrict__ b_hh,
    float* __restrict__ temporal)      // [BN][HH]
{
    const int tid  = threadIdx.x;
    const int lane = tid & 63;
    const int w    = tid >> 6;
    const int l15  = lane & 15;
    const int lg   = lane >> 4;
    const int m0   = blockIdx.x * 32;

    __shared__ unsigned int Hl[32][HP];  // packed bf16 hi(low16)|lo(high16)  ~16.9 KB
    __shared__ float G[32][GS];          // gate preacts: [0,256)=r,z summed; [256,384)=hn; [384,512)=inn  ~68 KB

    // ---- B-fragments for W_hh (registers, hi/lo split) ----
    bf16x8 Bh_h[3][4], Bh_l[3][4];
    #pragma unroll
    for (int nt = 0; nt < 3; ++nt) {
        const int ntg = w * 3 + nt;
        const int col = ntg * 16 + l15;     // gate-output row of W_hh
        #pragma unroll
        for (int kf = 0; kf < 4; ++kf) {
            // k-slots for (i,lg): k = kf*32 + lg*4 + (i&3) + 16*(i>>2)
            const float* wp = W_hh + col * 128 + kf * 32 + lg * 4;
            float4 c0 = *(const float4*)wp;
            float4 c1 = *(const float4*)(wp + 16);
            float v[8] = {c0.x, c0.y, c0.z, c0.w, c1.x, c1.y, c1.z, c1.w};
            bf16x8 hi, lo;
            #pragma unroll
            for (int i = 0; i < 8; ++i) {
                short hb = f2bf(v[i]);
                hi[i] = hb;
                lo[i] = f2bf(v[i] - bf2f(hb));
            }
            Bh_h[nt][kf] = hi; Bh_l[nt][kf] = lo;
        }
    }
    // ---- B-fragments for W_ih (+ bias row at k==16) ----
    bf16x8 Bi_h[3], Bi_l[3];
    #pragma unroll
    for (int nt = 0; nt < 3; ++nt) {
        const int ntg = w * 3 + nt;
        const int col = ntg * 16 + l15;
        const int gate = ntg >> 3;
        float4 c0 = *(const float4*)(W_ih + col * 16 + lg * 4);   // k = lg*4+0..3 (<16)
        float bias = (gate < 2) ? (b_ih[col] + b_hh[col]) : b_ih[col];
        float v[8] = {c0.x, c0.y, c0.z, c0.w,
                      (lg == 0) ? bias : 0.0f, 0.0f, 0.0f, 0.0f};  // k==16 -> bias
        bf16x8 hi, lo;
        #pragma unroll
        for (int i = 0; i < 8; ++i) {
            short hb = f2bf(v[i]);
            hi[i] = hb;
            lo[i] = f2bf(v[i] - bf2f(hb));
        }
        Bi_h[nt] = hi; Bi_l[nt] = lo;
    }

    // ---- gate-phase thread ownership: (gm, jb..jb+7) ----
    const int gm = tid >> 4;
    const int jb = (tid & 15) << 3;
    float bhn_[8], hprev_[8];
    #pragma unroll
    for (int u = 0; u < 8; ++u) { bhn_[u] = b_hh[256 + jb + u]; hprev_[u] = 0.0f; }

    for (int i = tid; i < 32 * HP; i += 512) (&Hl[0][0])[i] = 0u;
    __syncthreads();

    for (int t = 0; t < TT; ++t) {
        f32x4 ax[2][3], ah[2][3];
        #pragma unroll
        for (int mt = 0; mt < 2; ++mt)
            #pragma unroll
            for (int nt = 0; nt < 3; ++nt) {
                ax[mt][nt] = (f32x4){0.f, 0.f, 0.f, 0.f};
                ah[mt][nt] = (f32x4){0.f, 0.f, 0.f, 0.f};
            }

        #pragma unroll
        for (int mt = 0; mt < 2; ++mt) {
            // x fragment (k<16 data, k==16 ones column, rest zero)
            const float* xp = x + (size_t)(m0 + mt * 16 + l15) * (TT * FIN) + t * FIN + lg * 4;
            float4 xc = *(const float4*)xp;
            float xv[4] = {xc.x, xc.y, xc.z, xc.w};
            bf16x8 axh, axl;
            #pragma unroll
            for (int i = 0; i < 4; ++i) {
                short hb = f2bf(xv[i]);
                axh[i] = hb;
                axl[i] = f2bf(xv[i] - bf2f(hb));
            }
            axh[4] = (lg == 0) ? (short)0x3F80 : (short)0;  // bf16(1.0)
            axl[4] = 0;
            axh[5] = 0; axh[6] = 0; axh[7] = 0;
            axl[5] = 0; axl[6] = 0; axl[7] = 0;
            #pragma unroll
            for (int nt = 0; nt < 3; ++nt) {
                ax[mt][nt] = __builtin_amdgcn_mfma_f32_16x16x32_bf16(axh, Bi_h[nt], ax[mt][nt], 0, 0, 0);
                ax[mt][nt] = __builtin_amdgcn_mfma_f32_16x16x32_bf16(axh, Bi_l[nt], ax[mt][nt], 0, 0, 0);
                ax[mt][nt] = __builtin_amdgcn_mfma_f32_16x16x32_bf16(axl, Bi_h[nt], ax[mt][nt], 0, 0, 0);
            }
            // H fragments (packed hi|lo dwords)
            #pragma unroll
            for (int kf = 0; kf < 4; ++kf) {
                const unsigned int* hp = &Hl[mt * 16 + l15][kf * 32 + lg * 4];
                uint4 d0 = *(const uint4*)hp;
                uint4 d1 = *(const uint4*)(hp + 16);
                unsigned int dv[8] = {d0.x, d0.y, d0.z, d0.w, d1.x, d1.y, d1.z, d1.w};
                bf16x8 ahh, ahl;
                #pragma unroll
                for (int i = 0; i < 8; ++i) {
                    ahh[i] = (short)(dv[i] & 0xffffu);
                    ahl[i] = (short)(dv[i] >> 16);
                }
                #pragma unroll
                for (int nt = 0; nt < 3; ++nt) {
                    ah[mt][nt] = __builtin_amdgcn_mfma_f32_16x16x32_bf16(ahh, Bh_h[nt][kf], ah[mt][nt], 0, 0, 0);
                    ah[mt][nt] = __builtin_amdgcn_mfma_f32_16x16x32_bf16(ahh, Bh_l[nt][kf], ah[mt][nt], 0, 0, 0);
                    ah[mt][nt] = __builtin_amdgcn_mfma_f32_16x16x32_bf16(ahl, Bh_h[nt][kf], ah[mt][nt], 0, 0, 0);
                }
            }
        }

        // C write: r,z tiles -> sum; n tiles -> hn at native col, inn at col+128
        #pragma unroll
        for (int mt = 0; mt < 2; ++mt)
            #pragma unroll
            for (int nt = 0; nt < 3; ++nt) {
                const int ntg = w * 3 + nt;
                const int col = ntg * 16 + l15;
                const int row = mt * 16 + lg * 4;
                if (ntg < 16) {
                    #pragma unroll
                    for (int p = 0; p < 4; ++p)
                        G[row + p][col] = ax[mt][nt][p] + ah[mt][nt][p];
                } else {
                    #pragma unroll
                    for (int p = 0; p < 4; ++p) {
                        G[row + p][col]       = ah[mt][nt][p];
                        G[row + p][col + 128] = ax[mt][nt][p];
                    }
                }
            }
        __syncthreads();

        // gate math: thread owns (gm, jb..jb+7), h_prev fp32 in regs
        const float* g0 = &G[gm][jb];
        float4 R0 = *(const float4*)(g0);        float4 R1 = *(const float4*)(g0 + 4);
        float4 Z0 = *(const float4*)(g0 + 128);  float4 Z1 = *(const float4*)(g0 + 132);
        float4 N0 = *(const float4*)(g0 + 256);  float4 N1 = *(const float4*)(g0 + 260);
        float4 X0 = *(const float4*)(g0 + 384);  float4 X1 = *(const float4*)(g0 + 388);
        float rv[8] = {R0.x, R0.y, R0.z, R0.w, R1.x, R1.y, R1.z, R1.w};
        float zv[8] = {Z0.x, Z0.y, Z0.z, Z0.w, Z1.x, Z1.y, Z1.z, Z1.w};
        float nv[8] = {N0.x, N0.y, N0.z, N0.w, N1.x, N1.y, N1.z, N1.w};
        float xvv[8] = {X0.x, X0.y, X0.z, X0.w, X1.x, X1.y, X1.z, X1.w};
        unsigned int pk[8];
        #pragma unroll
        for (int u = 0; u < 8; ++u) {
            float r = 1.0f / (1.0f + __expf(-rv[u]));
            float z = 1.0f / (1.0f + __expf(-zv[u]));
            float pre = xvv[u] + r * (nv[u] + bhn_[u]);
            pre = fminf(fmaxf(pre, -20.0f), 20.0f);
            float e2 = __expf(2.0f * pre);
            float n = (e2 - 1.0f) / (e2 + 1.0f);
            float h = (1.0f - z) * n + z * hprev_[u];
            hprev_[u] = h;
            short hb = f2bf(h);
            short lb = f2bf(h - bf2f(hb));
            pk[u] = (unsigned int)(unsigned short)hb | ((unsigned int)(unsigned short)lb << 16);
        }
        *(uint4*)&Hl[gm][jb]     = make_uint4(pk[0], pk[1], pk[2], pk[3]);
        *(uint4*)&Hl[gm][jb + 4] = make_uint4(pk[4], pk[5], pk[6], pk[7]);
        __syncthreads();
    }

    float4 o0 = make_float4(hprev_[0], hprev_[1], hprev_[2], hprev_[3]);
    float4 o1 = make_float4(hprev_[4], hprev_[5], hprev_[6], hprev_[7]);
    float* op = temporal + (size_t)(m0 + gm) * HH + jb;
    *(float4*)op = o0;
    *(float4*)(op + 4) = o1;
}

// ---------------- fused GCN layer: gather + linear + LayerNorm + ReLU ----------------
__global__ __launch_bounds__(128) void gcn_kernel(
    const float* __restrict__ xin,     // [BB][NN][HH]
    const int* __restrict__ rowptr,    // [NN+1]
    const int* __restrict__ esrc,      // edges sorted by dst
    const float* __restrict__ enorm,
    const float* __restrict__ Wt,      // [HH][HH]  Wt[k][j] = W[j][k]
    const float* __restrict__ bias,
    const float* __restrict__ gma, const float* __restrict__ bta,
    float* __restrict__ out)           // [BB][NN][HH]
{
    const int n = blockIdx.x;
    const int j = threadIdx.x;
    const int beg = rowptr[n], end = rowptr[n + 1];

    float a0 = 0.f, a1 = 0.f, a2 = 0.f, a3 = 0.f;
    int e = beg;
    for (; e + 1 < end; e += 2) {
        int   s0 = esrc[e],   s1 = esrc[e + 1];
        float m0 = enorm[e],  m1 = enorm[e + 1];
        const float* p0 = xin + (size_t)s0 * HH + j;
        const float* p1 = xin + (size_t)s1 * HH + j;
        float v00 = p0[0], v01 = p0[NN*HH], v02 = p0[2*NN*HH], v03 = p0[3*NN*HH];
        float v10 = p1[0], v11 = p1[NN*HH], v12 = p1[2*NN*HH], v13 = p1[3*NN*HH];
        a0 = fmaf(m0, v00, a0); a1 = fmaf(m0, v01, a1);
        a2 = fmaf(m0, v02, a2); a3 = fmaf(m0, v03, a3);
        a0 = fmaf(m1, v10, a0); a1 = fmaf(m1, v11, a1);
        a2 = fmaf(m1, v12, a2); a3 = fmaf(m1, v13, a3);
    }
    if (e < end) {
        int s0 = esrc[e]; float m0 = enorm[e];
        const float* p0 = xin + (size_t)s0 * HH + j;
        a0 = fmaf(m0, p0[0],       a0); a1 = fmaf(m0, p0[NN*HH],   a1);
        a2 = fmaf(m0, p0[2*NN*HH], a2); a3 = fmaf(m0, p0[3*NN*HH], a3);
    }

    __shared__ __align__(16) float agg[BB][HH];
    agg[0][j] = a0; agg[1][j] = a1; agg[2][j] = a2; agg[3][j] = a3;
    __syncthreads();

    const float bj = bias[j];
    float c0 = bj, c1 = bj, c2 = bj, c3 = bj;
    #pragma unroll 4
    for (int k = 0; k < HH; ++k) {
        float w = Wt[k * HH + j];
        c0 = fmaf(w, agg[0][k], c0);
        c1 = fmaf(w, agg[1][k], c1);
        c2 = fmaf(w, agg[2][k], c2);
        c3 = fmaf(w, agg[3][k], c3);
    }

    const int lane = j & 63, wid = j >> 6;
    __shared__ float red[2][BB][2];
    const float gj = gma[j], btj = bta[j];

#define LNRED(cv, b) do { \
        float s1 = (cv), s2 = (cv) * (cv); \
        for (int off = 32; off >= 1; off >>= 1) { s1 += __shfl_down(s1, off); s2 += __shfl_down(s2, off); } \
        if (lane == 0) { red[wid][b][0] = s1; red[wid][b][1] = s2; } \
    } while (0)
    LNRED(c0, 0); LNRED(c1, 1); LNRED(c2, 2); LNRED(c3, 3);
    __syncthreads();

#define LNOUT(cv, b) do { \
        float s1 = red[0][b][0] + red[1][b][0]; \
        float s2 = red[0][b][1] + red[1][b][1]; \
        float mu = s1 * (1.0f / HH); \
        float var = s2 * (1.0f / HH) - mu * mu; \
        float y = ((cv) - mu) * rsqrtf(var + 1e-5f) * gj + btj; \
        out[((size_t)(b) * NN + n) * HH + j] = fmaxf(y, 0.0f); \
    } while (0)
    LNOUT(c0, 0); LNOUT(c1, 1); LNOUT(c2, 2); LNOUT(c3, 3);
#undef LNRED
#undef LNOUT
}

// ---------------- classifier (fused 2-layer MLP) ----------------
__global__ __launch_bounds__(128) void classifier_kernel(
    const float* __restrict__ tin,   // temporal [BN][HH]
    const float* __restrict__ sin_,  // spatial  [BN][HH]
    const float* __restrict__ Wt1,   // [2*HH][HH]
    const float* __restrict__ b1,
    const float* __restrict__ W2,    // [CC][HH]
    const float* __restrict__ b2,
    float* __restrict__ out)         // [BN][CC]
{
    const int j = threadIdx.x;
    const int r0 = blockIdx.x * 8;
    __shared__ __align__(16) float tb[HH][8];
    __shared__ __align__(16) float sb[HH][8];
    __shared__ __align__(16) float h1[HH][8];
    for (int i = j; i < 8 * HH; i += 128) {
        int r = i >> 7, k = i & 127;
        tb[k][r] = tin [(size_t)(r0 + r) * HH + k];
        sb[k][r] = sin_[(size_t)(r0 + r) * HH + k];
    }
    __syncthreads();

    float acc[8];
    float bj = b1[j];
    #pragma unroll
    for (int r = 0; r < 8; ++r) acc[r] = bj;
    #pragma unroll 2
    for (int k = 0; k < HH; ++k) {
        float w = Wt1[k * HH + j];
        float4 a  = *(const float4*)&tb[k][0];
        float4 b4 = *(const float4*)&tb[k][4];
        acc[0] = fmaf(w, a.x,  acc[0]); acc[1] = fmaf(w, a.y,  acc[1]);
        acc[2] = fmaf(w, a.z,  acc[2]); acc[3] = fmaf(w, a.w,  acc[3]);
        acc[4] = fmaf(w, b4.x, acc[4]); acc[5] = fmaf(w, b4.y, acc[5]);
        acc[6] = fmaf(w, b4.z, acc[6]); acc[7] = fmaf(w, b4.w, acc[7]);
    }
    #pragma unroll 2
    for (int k = 0; k < HH; ++k) {
        float w = Wt1[(HH + k) * HH + j];
        float4 a  = *(const float4*)&sb[k][0];
        float4 b4 = *(const float4*)&sb[k][4];
        acc[0] = fmaf(w, a.x,  acc[0]); acc[1] = fmaf(w, a.y,  acc[1]);
        acc[2] = fmaf(w, a.z,  acc[2]); acc[3] = fmaf(w, a.w,  acc[3]);
        acc[4] = fmaf(w, b4.x, acc[4]); acc[5] = fmaf(w, b4.y, acc[5]);
        acc[6] = fmaf(w, b4.z, acc[6]); acc[7] = fmaf(w, b4.w, acc[7]);
    }
    #pragma unroll
    for (int r = 0; r < 8; ++r) h1[j][r] = fmaxf(acc[r], 0.0f);
    __syncthreads();

    if (j < 8 * CC) {
        int r = j / CC, c = j - r * CC;
        float a = b2[c];
        for (int k = 0; k < HH; ++k) a = fmaf(W2[c * HH + k], h1[k][r], a);
        out[(size_t)(r0 + r) * CC + c] = a;
    }
}

// ---------------- launch ----------------
extern "C" void kernel_launch(void* const* d_in, const int* in_sizes, int n_in,
                              void* d_out, int out_size, void* d_ws, size_t ws_size,
                              hipStream_t stream) {
    const float* x    = (const float*)d_in[0];
    const int*   ei   = (const int*)  d_in[1];
    const float* W_ih = (const float*)d_in[2];
    const float* W_hh = (const float*)d_in[3];
    const float* b_ih = (const float*)d_in[4];
    const float* b_hh = (const float*)d_in[5];
    const float* gW1  = (const float*)d_in[6];
    const float* gb1  = (const float*)d_in[7];
    const float* gW2  = (const float*)d_in[8];
    const float* gb2  = (const float*)d_in[9];
    const float* lg1  = (const float*)d_in[10];
    const float* lb1  = (const float*)d_in[11];
    const float* lg2  = (const float*)d_in[12];
    const float* lb2  = (const float*)d_in[13];
    const float* cW1  = (const float*)d_in[14];
    const float* cb1  = (const float*)d_in[15];
    const float* cW2  = (const float*)d_in[16];
    const float* cb2  = (const float*)d_in[17];
    float* out = (float*)d_out;

    float* ws = (float*)d_ws;
    float* Wt_g1 = ws;  ws += 128 * 128;
    float* Wt_g2 = ws;  ws += 128 * 128;
    float* Wt_c1 = ws;  ws += 256 * 128;
    float* dis   = ws;  ws += 2048;
    float* enorm = ws;  ws += EE;
    float* temporal = ws; ws += (size_t)BN * HH;
    float* sA    = ws;  ws += (size_t)BN * HH;
    float* sB    = ws;  ws += (size_t)BN * HH;
    int* ip      = (int*)ws;
    int* cnt     = ip;  ip += 2048;
    int* rowptr  = ip;  ip += 2080;
    int* cursor  = ip;  ip += 2048;
    int* esrc    = ip;  ip += EE;

    const int* srcp = ei;
    const int* dstp = ei + EE;

    hipMemsetAsync(cnt, 0, 2048 * sizeof(int), stream);

    transpose_kernel<<<64, 256, 0, stream>>>(gW1, Wt_g1, 128, 128);
    transpose_kernel<<<64, 256, 0, stream>>>(gW2, Wt_g2, 128, 128);
    transpose_kernel<<<128, 256, 0, stream>>>(cW1, Wt_c1, 128, 256);

    cnt_kernel<<<250, 256, 0, stream>>>(dstp, cnt);
    scan_kernel<<<1, 256, 0, stream>>>(cnt, rowptr, cursor);
    dis_kernel<<<8, 256, 0, stream>>>(cnt, dis);
    csr_fill_kernel<<<250, 256, 0, stream>>>(srcp, dstp, dis, cursor, esrc, enorm);

    gru_mfma_kernel<<<BN / 32, 512, 0, stream>>>(x, W_hh, W_ih, b_ih, b_hh, temporal);

    gcn_kernel<<<NN, 128, 0, stream>>>(temporal, rowptr, esrc, enorm, Wt_g1, gb1, lg1, lb1, sA);
    gcn_kernel<<<NN, 128, 0, stream>>>(sA, rowptr, esrc, enorm, Wt_g2, gb2, lg2, lb2, sB);

    classifier_kernel<<<BN / 8, 128, 0, stream>>>(temporal, sB, Wt_c1, cb1, cW2, cb2, out);
}

// Round 6
// 206.311 us; speedup vs baseline: 55.2997x; 1.1344x over previous
//
#include <hip/hip_runtime.h>
#include <math.h>

#define BB  4
#define NN  2000
#define TT  24
#define FIN 16
#define HH  128
#define EE  64000
#define CC  6
#define BN  (BB*NN)   // 8000

typedef _Float16 f16x8 __attribute__((ext_vector_type(8)));
typedef float f32x4 __attribute__((ext_vector_type(4)));

// ---------------- prep kernels ----------------
__global__ void transpose_kernel(const float* __restrict__ in, float* __restrict__ out,
                                 int R, int C) {
    int idx = blockIdx.x * 256 + threadIdx.x;
    if (idx < R * C) {
        int r = idx / C, c = idx - r * C;
        out[c * R + r] = in[idx];
    }
}

__global__ void cnt_kernel(const int* __restrict__ dst, int* __restrict__ cnt) {
    int e = blockIdx.x * 256 + threadIdx.x;
    if (e < EE) atomicAdd(&cnt[dst[e]], 1);
}

__global__ __launch_bounds__(256) void scan_kernel(const int* __restrict__ cnt,
                                                   int* __restrict__ rowptr,
                                                   int* __restrict__ cursor) {
    __shared__ int part[256];
    int tid = threadIdx.x;
    int base = tid * 8;
    int loc[8]; int s = 0;
    #pragma unroll
    for (int u = 0; u < 8; ++u) {
        int v = (base + u < NN) ? cnt[base + u] : 0;
        loc[u] = s; s += v;
    }
    part[tid] = s;
    __syncthreads();
    #pragma unroll
    for (int off = 1; off < 256; off <<= 1) {
        int add = (tid >= off) ? part[tid - off] : 0;
        __syncthreads();
        part[tid] += add;
        __syncthreads();
    }
    int offset = (tid > 0) ? part[tid - 1] : 0;
    #pragma unroll
    for (int u = 0; u < 8; ++u) {
        int idx = base + u;
        if (idx < NN) { rowptr[idx] = offset + loc[u]; cursor[idx] = offset + loc[u]; }
    }
    if (tid == 255) rowptr[NN] = part[255];
}

__global__ void dis_kernel(const int* __restrict__ cnt, float* __restrict__ dis) {
    int n = blockIdx.x * 256 + threadIdx.x;
    if (n < NN) dis[n] = rsqrtf(fmaxf((float)cnt[n], 1.0f));
}

__global__ void csr_fill_kernel(const int* __restrict__ src, const int* __restrict__ dst,
                                const float* __restrict__ dis, int* __restrict__ cursor,
                                int* __restrict__ esrc, float* __restrict__ enorm) {
    int e = blockIdx.x * 256 + threadIdx.x;
    if (e < EE) {
        int d = dst[e], s = src[e];
        int pos = atomicAdd(&cursor[d], 1);
        esrc[pos] = s;
        enorm[pos] = dis[s] * dis[d];
    }
}

// ---------------- GRU via MFMA (unit-ownership, fp16, in-register gates) ----------------
// Block = 512 thr = 8 waves, 32 seqs, all 24 steps. Wave w owns units [w*16, w*16+16)
// across ALL THREE gates (tiles at cols w*16, 128+w*16, 256+w*16) -> r,z,hn,inn for a
// (seq,unit) pair land in the SAME lane & reg -> gate math fully in registers, no G LDS.
// Lane (l15,lg): unit u = w*16+l15 (one unit), seqs = {mt*16 + lg*4 + p}.
// k-map (A and B identical, bijective per MFMA => contraction-invariant):
//   hh: k = kf*32 + lg*8 + i   (i=0..7, kf=0..3)
//   ih: k = lg*8 + i           (k<16 data, k==16 ones/bias, rest zero)
// Precision: A (h, x) fp16 hi/lo 2-term; B (weights) single fp16 (err 2^-11).
// H state: separate Hhi/Hlo ushort arrays (direct b128 A-frag reads, no unpack VALU),
// double-buffered -> ONE barrier per step. Stride 136 ushorts = 272B: 16B-aligned rows,
// uniform 8 accesses/bank per b128 wave-read (optimal for 1KB/instr).
// NO launch_bounds min-occupancy arg (R2/R3 lesson: forced VGPR caps -> GB-scale spill).
#define HP2 136

__global__ __launch_bounds__(512) void gru_mfma_kernel(
    const float* __restrict__ x,       // [BN][TT][FIN]
    const float* __restrict__ W_hh,    // [384][128]
    const float* __restrict__ W_ih,    // [384][16]
    const float* __restrict__ b_ih, const float* __restrict__ b_hh,
    float* __restrict__ temporal)      // [BN][HH]
{
    const int tid  = threadIdx.x;
    const int lane = tid & 63;
    const int w    = tid >> 6;
    const int l15  = lane & 15;
    const int lg   = lane >> 4;
    const int m0   = blockIdx.x * 32;
    const int u    = w * 16 + l15;

    __shared__ __align__(16) unsigned short Hhi[2][32][HP2];  // 17 KB
    __shared__ __align__(16) unsigned short Hlo[2][32][HP2];  // 17 KB

    // ---- B-fragments: W_hh (fp16 single), 3 gates x 4 kf ----
    f16x8 Bh[3][4];
    #pragma unroll
    for (int g = 0; g < 3; ++g) {
        const int col = g * 128 + u;
        #pragma unroll
        for (int kf = 0; kf < 4; ++kf) {
            const float* wp = W_hh + col * 128 + kf * 32 + lg * 8;
            float4 c0 = *(const float4*)wp;
            float4 c1 = *(const float4*)(wp + 4);
            f16x8 b;
            b[0] = (_Float16)c0.x; b[1] = (_Float16)c0.y;
            b[2] = (_Float16)c0.z; b[3] = (_Float16)c0.w;
            b[4] = (_Float16)c1.x; b[5] = (_Float16)c1.y;
            b[6] = (_Float16)c1.z; b[7] = (_Float16)c1.w;
            Bh[g][kf] = b;
        }
    }
    // ---- B-fragments: W_ih + bias at k==16 ----
    f16x8 Bi[3];
    #pragma unroll
    for (int g = 0; g < 3; ++g) {
        const int col = g * 128 + u;
        f16x8 b;
        #pragma unroll
        for (int i = 0; i < 8; ++i) b[i] = (_Float16)0.0f;
        if (lg < 2) {
            const float* wp = W_ih + col * 16 + lg * 8;
            float4 c0 = *(const float4*)wp;
            float4 c1 = *(const float4*)(wp + 4);
            b[0] = (_Float16)c0.x; b[1] = (_Float16)c0.y;
            b[2] = (_Float16)c0.z; b[3] = (_Float16)c0.w;
            b[4] = (_Float16)c1.x; b[5] = (_Float16)c1.y;
            b[6] = (_Float16)c1.z; b[7] = (_Float16)c1.w;
        } else if (lg == 2) {
            float bias = b_ih[col] + ((g < 2) ? b_hh[col] : 0.0f);
            b[0] = (_Float16)bias;   // k == 16
        }
        Bi[g] = b;
    }

    const float bhn = b_hh[256 + u];
    float hprev[2][4];
    #pragma unroll
    for (int mt = 0; mt < 2; ++mt)
        #pragma unroll
        for (int p = 0; p < 4; ++p) hprev[mt][p] = 0.0f;

    // init h = 0 in buffer 0
    for (int i = tid; i < 32 * HP2; i += 512) {
        (&Hhi[0][0][0])[i] = 0;
        (&Hlo[0][0][0])[i] = 0;
    }
    __syncthreads();

    for (int t = 0; t < TT; ++t) {
        const int rb = t & 1, wb = rb ^ 1;

        f32x4 aR[2], aZ[2], aH[2], aI[2];
        #pragma unroll
        for (int mt = 0; mt < 2; ++mt) {
            aR[mt] = (f32x4){0.f, 0.f, 0.f, 0.f};
            aZ[mt] = (f32x4){0.f, 0.f, 0.f, 0.f};
            aH[mt] = (f32x4){0.f, 0.f, 0.f, 0.f};
            aI[mt] = (f32x4){0.f, 0.f, 0.f, 0.f};
        }

        #pragma unroll
        for (int mt = 0; mt < 2; ++mt) {
            // ---- x fragment: k<16 data, k==16 ones, rest zero ----
            f16x8 axh, axl;
            #pragma unroll
            for (int i = 0; i < 8; ++i) { axh[i] = (_Float16)0.0f; axl[i] = (_Float16)0.0f; }
            if (lg < 2) {
                const float* xp = x + (size_t)(m0 + mt * 16 + l15) * (TT * FIN) + t * FIN + lg * 8;
                float4 c0 = *(const float4*)xp;
                float4 c1 = *(const float4*)(xp + 4);
                float xv[8] = {c0.x, c0.y, c0.z, c0.w, c1.x, c1.y, c1.z, c1.w};
                #pragma unroll
                for (int i = 0; i < 8; ++i) {
                    _Float16 hb = (_Float16)xv[i];
                    axh[i] = hb;
                    axl[i] = (_Float16)(xv[i] - (float)hb);
                }
            } else if (lg == 2) {
                axh[0] = (_Float16)1.0f;  // k == 16: ones column (bias)
            }
            aR[mt] = __builtin_amdgcn_mfma_f32_16x16x32_f16(axh, Bi[0], aR[mt], 0, 0, 0);
            aR[mt] = __builtin_amdgcn_mfma_f32_16x16x32_f16(axl, Bi[0], aR[mt], 0, 0, 0);
            aZ[mt] = __builtin_amdgcn_mfma_f32_16x16x32_f16(axh, Bi[1], aZ[mt], 0, 0, 0);
            aZ[mt] = __builtin_amdgcn_mfma_f32_16x16x32_f16(axl, Bi[1], aZ[mt], 0, 0, 0);
            aI[mt] = __builtin_amdgcn_mfma_f32_16x16x32_f16(axh, Bi[2], aI[mt], 0, 0, 0);
            aI[mt] = __builtin_amdgcn_mfma_f32_16x16x32_f16(axl, Bi[2], aI[mt], 0, 0, 0);

            // ---- H fragments: direct b128 reads, no unpack ----
            #pragma unroll
            for (int kf = 0; kf < 4; ++kf) {
                const int seq = mt * 16 + l15;
                const int ko  = kf * 32 + lg * 8;
                f16x8 ahh = *(const f16x8*)&Hhi[rb][seq][ko];
                f16x8 ahl = *(const f16x8*)&Hlo[rb][seq][ko];
                aR[mt] = __builtin_amdgcn_mfma_f32_16x16x32_f16(ahh, Bh[0][kf], aR[mt], 0, 0, 0);
                aR[mt] = __builtin_amdgcn_mfma_f32_16x16x32_f16(ahl, Bh[0][kf], aR[mt], 0, 0, 0);
                aZ[mt] = __builtin_amdgcn_mfma_f32_16x16x32_f16(ahh, Bh[1][kf], aZ[mt], 0, 0, 0);
                aZ[mt] = __builtin_amdgcn_mfma_f32_16x16x32_f16(ahl, Bh[1][kf], aZ[mt], 0, 0, 0);
                aH[mt] = __builtin_amdgcn_mfma_f32_16x16x32_f16(ahh, Bh[2][kf], aH[mt], 0, 0, 0);
                aH[mt] = __builtin_amdgcn_mfma_f32_16x16x32_f16(ahl, Bh[2][kf], aH[mt], 0, 0, 0);
            }
        }

        // ---- gate math, fully in registers ----
        #pragma unroll
        for (int mt = 0; mt < 2; ++mt) {
            #pragma unroll
            for (int p = 0; p < 4; ++p) {
                float r = 1.0f / (1.0f + __expf(-aR[mt][p]));
                float z = 1.0f / (1.0f + __expf(-aZ[mt][p]));
                float pre = aI[mt][p] + r * (aH[mt][p] + bhn);
                pre = fminf(fmaxf(pre, -20.0f), 20.0f);
                float e2 = __expf(2.0f * pre);
                float n = (e2 - 1.0f) / (e2 + 1.0f);
                float h = (1.0f - z) * n + z * hprev[mt][p];
                hprev[mt][p] = h;
                _Float16 hb = (_Float16)h;
                _Float16 lb = (_Float16)(h - (float)hb);
                const int seq = mt * 16 + lg * 4 + p;
                Hhi[wb][seq][u] = *(unsigned short*)&hb;
                Hlo[wb][seq][u] = *(unsigned short*)&lb;
            }
        }
        __syncthreads();
    }

    #pragma unroll
    for (int mt = 0; mt < 2; ++mt)
        #pragma unroll
        for (int p = 0; p < 4; ++p) {
            const int seq = mt * 16 + lg * 4 + p;
            temporal[(size_t)(m0 + seq) * HH + u] = hprev[mt][p];
        }
}

// ---------------- fused GCN layer: gather + linear + LayerNorm + ReLU ----------------
__global__ __launch_bounds__(128) void gcn_kernel(
    const float* __restrict__ xin,     // [BB][NN][HH]
    const int* __restrict__ rowptr,    // [NN+1]
    const int* __restrict__ esrc,      // edges sorted by dst
    const float* __restrict__ enorm,
    const float* __restrict__ Wt,      // [HH][HH]  Wt[k][j] = W[j][k]
    const float* __restrict__ bias,
    const float* __restrict__ gma, const float* __restrict__ bta,
    float* __restrict__ out)           // [BB][NN][HH]
{
    const int n = blockIdx.x;
    const int j = threadIdx.x;
    const int beg = rowptr[n], end = rowptr[n + 1];

    float a0 = 0.f, a1 = 0.f, a2 = 0.f, a3 = 0.f;
    int e = beg;
    for (; e + 1 < end; e += 2) {
        int   s0 = esrc[e],   s1 = esrc[e + 1];
        float m0 = enorm[e],  m1 = enorm[e + 1];
        const float* p0 = xin + (size_t)s0 * HH + j;
        const float* p1 = xin + (size_t)s1 * HH + j;
        float v00 = p0[0], v01 = p0[NN*HH], v02 = p0[2*NN*HH], v03 = p0[3*NN*HH];
        float v10 = p1[0], v11 = p1[NN*HH], v12 = p1[2*NN*HH], v13 = p1[3*NN*HH];
        a0 = fmaf(m0, v00, a0); a1 = fmaf(m0, v01, a1);
        a2 = fmaf(m0, v02, a2); a3 = fmaf(m0, v03, a3);
        a0 = fmaf(m1, v10, a0); a1 = fmaf(m1, v11, a1);
        a2 = fmaf(m1, v12, a2); a3 = fmaf(m1, v13, a3);
    }
    if (e < end) {
        int s0 = esrc[e]; float m0 = enorm[e];
        const float* p0 = xin + (size_t)s0 * HH + j;
        a0 = fmaf(m0, p0[0],       a0); a1 = fmaf(m0, p0[NN*HH],   a1);
        a2 = fmaf(m0, p0[2*NN*HH], a2); a3 = fmaf(m0, p0[3*NN*HH], a3);
    }

    __shared__ __align__(16) float agg[BB][HH];
    agg[0][j] = a0; agg[1][j] = a1; agg[2][j] = a2; agg[3][j] = a3;
    __syncthreads();

    const float bj = bias[j];
    float c0 = bj, c1 = bj, c2 = bj, c3 = bj;
    #pragma unroll 4
    for (int k = 0; k < HH; ++k) {
        float w = Wt[k * HH + j];
        c0 = fmaf(w, agg[0][k], c0);
        c1 = fmaf(w, agg[1][k], c1);
        c2 = fmaf(w, agg[2][k], c2);
        c3 = fmaf(w, agg[3][k], c3);
    }

    const int lane = j & 63, wid = j >> 6;
    __shared__ float red[2][BB][2];
    const float gj = gma[j], btj = bta[j];

#define LNRED(cv, b) do { \
        float s1 = (cv), s2 = (cv) * (cv); \
        for (int off = 32; off >= 1; off >>= 1) { s1 += __shfl_down(s1, off); s2 += __shfl_down(s2, off); } \
        if (lane == 0) { red[wid][b][0] = s1; red[wid][b][1] = s2; } \
    } while (0)
    LNRED(c0, 0); LNRED(c1, 1); LNRED(c2, 2); LNRED(c3, 3);
    __syncthreads();

#define LNOUT(cv, b) do { \
        float s1 = red[0][b][0] + red[1][b][0]; \
        float s2 = red[0][b][1] + red[1][b][1]; \
        float mu = s1 * (1.0f / HH); \
        float var = s2 * (1.0f / HH) - mu * mu; \
        float y = ((cv) - mu) * rsqrtf(var + 1e-5f) * gj + btj; \
        out[((size_t)(b) * NN + n) * HH + j] = fmaxf(y, 0.0f); \
    } while (0)
    LNOUT(c0, 0); LNOUT(c1, 1); LNOUT(c2, 2); LNOUT(c3, 3);
#undef LNRED
#undef LNOUT
}

// ---------------- classifier (fused 2-layer MLP) ----------------
__global__ __launch_bounds__(128) void classifier_kernel(
    const float* __restrict__ tin,   // temporal [BN][HH]
    const float* __restrict__ sin_,  // spatial  [BN][HH]
    const float* __restrict__ Wt1,   // [2*HH][HH]
    const float* __restrict__ b1,
    const float* __restrict__ W2,    // [CC][HH]
    const float* __restrict__ b2,
    float* __restrict__ out)         // [BN][CC]
{
    const int j = threadIdx.x;
    const int r0 = blockIdx.x * 8;
    __shared__ __align__(16) float tb[HH][8];
    __shared__ __align__(16) float sb[HH][8];
    __shared__ __align__(16) float h1[HH][8];
    for (int i = j; i < 8 * HH; i += 128) {
        int r = i >> 7, k = i & 127;
        tb[k][r] = tin [(size_t)(r0 + r) * HH + k];
        sb[k][r] = sin_[(size_t)(r0 + r) * HH + k];
    }
    __syncthreads();

    float acc[8];
    float bj = b1[j];
    #pragma unroll
    for (int r = 0; r < 8; ++r) acc[r] = bj;
    #pragma unroll 2
    for (int k = 0; k < HH; ++k) {
        float w = Wt1[k * HH + j];
        float4 a  = *(const float4*)&tb[k][0];
        float4 b4 = *(const float4*)&tb[k][4];
        acc[0] = fmaf(w, a.x,  acc[0]); acc[1] = fmaf(w, a.y,  acc[1]);
        acc[2] = fmaf(w, a.z,  acc[2]); acc[3] = fmaf(w, a.w,  acc[3]);
        acc[4] = fmaf(w, b4.x, acc[4]); acc[5] = fmaf(w, b4.y, acc[5]);
        acc[6] = fmaf(w, b4.z, acc[6]); acc[7] = fmaf(w, b4.w, acc[7]);
    }
    #pragma unroll 2
    for (int k = 0; k < HH; ++k) {
        float w = Wt1[(HH + k) * HH + j];
        float4 a  = *(const float4*)&sb[k][0];
        float4 b4 = *(const float4*)&sb[k][4];
        acc[0] = fmaf(w, a.x,  acc[0]); acc[1] = fmaf(w, a.y,  acc[1]);
        acc[2] = fmaf(w, a.z,  acc[2]); acc[3] = fmaf(w, a.w,  acc[3]);
        acc[4] = fmaf(w, b4.x, acc[4]); acc[5] = fmaf(w, b4.y, acc[5]);
        acc[6] = fmaf(w, b4.z, acc[6]); acc[7] = fmaf(w, b4.w, acc[7]);
    }
    #pragma unroll
    for (int r = 0; r < 8; ++r) h1[j][r] = fmaxf(acc[r], 0.0f);
    __syncthreads();

    if (j < 8 * CC) {
        int r = j / CC, c = j - r * CC;
        float a = b2[c];
        for (int k = 0; k < HH; ++k) a = fmaf(W2[c * HH + k], h1[k][r], a);
        out[(size_t)(r0 + r) * CC + c] = a;
    }
}

// ---------------- launch ----------------
extern "C" void kernel_launch(void* const* d_in, const int* in_sizes, int n_in,
                              void* d_out, int out_size, void* d_ws, size_t ws_size,
                              hipStream_t stream) {
    const float* x    = (const float*)d_in[0];
    const int*   ei   = (const int*)  d_in[1];
    const float* W_ih = (const float*)d_in[2];
    const float* W_hh = (const float*)d_in[3];
    const float* b_ih = (const float*)d_in[4];
    const float* b_hh = (const float*)d_in[5];
    const float* gW1  = (const float*)d_in[6];
    const float* gb1  = (const float*)d_in[7];
    const float* gW2  = (const float*)d_in[8];
    const float* gb2  = (const float*)d_in[9];
    const float* lg1  = (const float*)d_in[10];
    const float* lb1  = (const float*)d_in[11];
    const float* lg2  = (const float*)d_in[12];
    const float* lb2  = (const float*)d_in[13];
    const float* cW1  = (const float*)d_in[14];
    const float* cb1  = (const float*)d_in[15];
    const float* cW2  = (const float*)d_in[16];
    const float* cb2  = (const float*)d_in[17];
    float* out = (float*)d_out;

    float* ws = (float*)d_ws;
    float* Wt_g1 = ws;  ws += 128 * 128;
    float* Wt_g2 = ws;  ws += 128 * 128;
    float* Wt_c1 = ws;  ws += 256 * 128;
    float* dis   = ws;  ws += 2048;
    float* enorm = ws;  ws += EE;
    float* temporal = ws; ws += (size_t)BN * HH;
    float* sA    = ws;  ws += (size_t)BN * HH;
    float* sB    = ws;  ws += (size_t)BN * HH;
    int* ip      = (int*)ws;
    int* cnt     = ip;  ip += 2048;
    int* rowptr  = ip;  ip += 2080;
    int* cursor  = ip;  ip += 2048;
    int* esrc    = ip;  ip += EE;

    const int* srcp = ei;
    const int* dstp = ei + EE;

    hipMemsetAsync(cnt, 0, 2048 * sizeof(int), stream);

    transpose_kernel<<<64, 256, 0, stream>>>(gW1, Wt_g1, 128, 128);
    transpose_kernel<<<64, 256, 0, stream>>>(gW2, Wt_g2, 128, 128);
    transpose_kernel<<<128, 256, 0, stream>>>(cW1, Wt_c1, 128, 256);

    cnt_kernel<<<250, 256, 0, stream>>>(dstp, cnt);
    scan_kernel<<<1, 256, 0, stream>>>(cnt, rowptr, cursor);
    dis_kernel<<<8, 256, 0, stream>>>(cnt, dis);
    csr_fill_kernel<<<250, 256, 0, stream>>>(srcp, dstp, dis, cursor, esrc, enorm);

    gru_mfma_kernel<<<BN / 32, 512, 0, stream>>>(x, W_hh, W_ih, b_ih, b_hh, temporal);

    gcn_kernel<<<NN, 128, 0, stream>>>(temporal, rowptr, esrc, enorm, Wt_g1, gb1, lg1, lb1, sA);
    gcn_kernel<<<NN, 128, 0, stream>>>(sA, rowptr, esrc, enorm, Wt_g2, gb2, lg2, lb2, sB);

    classifier_kernel<<<BN / 8, 128, 0, stream>>>(temporal, sB, Wt_c1, cb1, cW2, cb2, out);
}

// Round 7
// 181.254 us; speedup vs baseline: 62.9444x; 1.1382x over previous
//
#include <hip/hip_runtime.h>
#include <math.h>

#define BB  4
#define NN  2000
#define TT  24
#define FIN 16
#define HH  128
#define EE  64000
#define CC  6
#define BN  (BB*NN)   // 8000

typedef _Float16 f16x8 __attribute__((ext_vector_type(8)));
typedef float f32x4 __attribute__((ext_vector_type(4)));

// ---------------- prep kernels ----------------
// one kernel, three transposes (ranges by blockIdx): gW1, gW2 (128x128), cW1 (128x256)
__global__ void fused_transpose_kernel(const float* __restrict__ gW1,
                                       const float* __restrict__ gW2,
                                       const float* __restrict__ cW1,
                                       float* __restrict__ o1, float* __restrict__ o2,
                                       float* __restrict__ o3) {
    int b = blockIdx.x;
    int tid = threadIdx.x;
    if (b < 64) {
        int idx = b * 256 + tid;                  // 128x128
        int r = idx >> 7, c = idx & 127;
        o1[c * 128 + r] = gW1[idx];
    } else if (b < 128) {
        int idx = (b - 64) * 256 + tid;
        int r = idx >> 7, c = idx & 127;
        o2[c * 128 + r] = gW2[idx];
    } else {
        int idx = (b - 128) * 256 + tid;          // 128x256
        int r = idx >> 8, c = idx & 255;
        o3[c * 128 + r] = cW1[idx];
    }
}

__global__ void cnt_kernel(const int* __restrict__ dst, int* __restrict__ cnt) {
    int e = blockIdx.x * 256 + threadIdx.x;
    if (e < EE) atomicAdd(&cnt[dst[e]], 1);
}

// scan + dis fused (single block)
__global__ __launch_bounds__(256) void scan_kernel(const int* __restrict__ cnt,
                                                   int* __restrict__ rowptr,
                                                   int* __restrict__ cursor,
                                                   float* __restrict__ dis) {
    __shared__ int part[256];
    int tid = threadIdx.x;
    int base = tid * 8;
    int loc[8]; int s = 0;
    #pragma unroll
    for (int u = 0; u < 8; ++u) {
        int v = (base + u < NN) ? cnt[base + u] : 0;
        loc[u] = s; s += v;
    }
    part[tid] = s;
    __syncthreads();
    #pragma unroll
    for (int off = 1; off < 256; off <<= 1) {
        int add = (tid >= off) ? part[tid - off] : 0;
        __syncthreads();
        part[tid] += add;
        __syncthreads();
    }
    int offset = (tid > 0) ? part[tid - 1] : 0;
    #pragma unroll
    for (int u = 0; u < 8; ++u) {
        int idx = base + u;
        if (idx < NN) {
            rowptr[idx] = offset + loc[u];
            cursor[idx] = offset + loc[u];
            dis[idx] = rsqrtf(fmaxf((float)cnt[idx], 1.0f));
        }
    }
    if (tid == 255) rowptr[NN] = part[255];
}

__global__ void csr_fill_kernel(const int* __restrict__ src, const int* __restrict__ dst,
                                const float* __restrict__ dis, int* __restrict__ cursor,
                                int* __restrict__ esrc, float* __restrict__ enorm) {
    int e = blockIdx.x * 256 + threadIdx.x;
    if (e < EE) {
        int d = dst[e], s = src[e];
        int pos = atomicAdd(&cursor[d], 1);
        esrc[pos] = s;
        enorm[pos] = dis[s] * dis[d];
    }
}

// ---------------- GRU via MFMA (16 seqs/block -> 500 blocks, 2 blocks/CU) ----------------
// R5 was grid-limited: 250 blocks = 1 block/CU = 2 waves/SIMD, latency-bound (Occ 21%).
// Now: block = 512 thr = 8 waves owns 16 seqs; wave w owns units [w*16,w*16+16) across
// all 3 gates; r,z,hn,inn for a (seq,unit) land in same lane+reg -> gate math in regs.
// k-map (A==B, bijective per MFMA): hh k = kf*32+lg*8+i; ih k = lg*8+i (k==16 bias col).
// A (h,x) fp16 hi/lo 2-term; B (W) single fp16. H dbuf in LDS -> 1 barrier/step.
// NO launch_bounds min-occupancy arg (R2/R3: forced VGPR caps -> GB-scale spill).
#define HP2 136

__global__ __launch_bounds__(512) void gru_mfma_kernel(
    const float* __restrict__ x,       // [BN][TT][FIN]
    const float* __restrict__ W_hh,    // [384][128]
    const float* __restrict__ W_ih,    // [384][16]
    const float* __restrict__ b_ih, const float* __restrict__ b_hh,
    float* __restrict__ temporal)      // [BN][HH]
{
    const int tid  = threadIdx.x;
    const int lane = tid & 63;
    const int w    = tid >> 6;
    const int l15  = lane & 15;
    const int lg   = lane >> 4;
    const int m0   = blockIdx.x * 16;
    const int u    = w * 16 + l15;

    __shared__ __align__(16) unsigned short Hhi[2][16][HP2];  // 8.5 KB
    __shared__ __align__(16) unsigned short Hlo[2][16][HP2];  // 8.5 KB

    // ---- B-fragments: W_hh (fp16 single), 3 gates x 4 kf ----
    f16x8 Bh[3][4];
    #pragma unroll
    for (int g = 0; g < 3; ++g) {
        const int col = g * 128 + u;
        #pragma unroll
        for (int kf = 0; kf < 4; ++kf) {
            const float* wp = W_hh + col * 128 + kf * 32 + lg * 8;
            float4 c0 = *(const float4*)wp;
            float4 c1 = *(const float4*)(wp + 4);
            f16x8 b;
            b[0] = (_Float16)c0.x; b[1] = (_Float16)c0.y;
            b[2] = (_Float16)c0.z; b[3] = (_Float16)c0.w;
            b[4] = (_Float16)c1.x; b[5] = (_Float16)c1.y;
            b[6] = (_Float16)c1.z; b[7] = (_Float16)c1.w;
            Bh[g][kf] = b;
        }
    }
    // ---- B-fragments: W_ih + bias at k==16 ----
    f16x8 Bi[3];
    #pragma unroll
    for (int g = 0; g < 3; ++g) {
        const int col = g * 128 + u;
        f16x8 b;
        #pragma unroll
        for (int i = 0; i < 8; ++i) b[i] = (_Float16)0.0f;
        if (lg < 2) {
            const float* wp = W_ih + col * 16 + lg * 8;
            float4 c0 = *(const float4*)wp;
            float4 c1 = *(const float4*)(wp + 4);
            b[0] = (_Float16)c0.x; b[1] = (_Float16)c0.y;
            b[2] = (_Float16)c0.z; b[3] = (_Float16)c0.w;
            b[4] = (_Float16)c1.x; b[5] = (_Float16)c1.y;
            b[6] = (_Float16)c1.z; b[7] = (_Float16)c1.w;
        } else if (lg == 2) {
            float bias = b_ih[col] + ((g < 2) ? b_hh[col] : 0.0f);
            b[0] = (_Float16)bias;   // k == 16
        }
        Bi[g] = b;
    }

    const float bhn = b_hh[256 + u];
    float hprev[4] = {0.0f, 0.0f, 0.0f, 0.0f};

    for (int i = tid; i < 16 * HP2; i += 512) {
        (&Hhi[0][0][0])[i] = 0;
        (&Hlo[0][0][0])[i] = 0;
    }
    __syncthreads();

    for (int t = 0; t < TT; ++t) {
        const int rb = t & 1, wb = rb ^ 1;

        f32x4 aR = (f32x4){0.f, 0.f, 0.f, 0.f};
        f32x4 aZ = (f32x4){0.f, 0.f, 0.f, 0.f};
        f32x4 aH = (f32x4){0.f, 0.f, 0.f, 0.f};
        f32x4 aI = (f32x4){0.f, 0.f, 0.f, 0.f};

        // ---- x fragment: k<16 data, k==16 ones, rest zero ----
        f16x8 axh, axl;
        #pragma unroll
        for (int i = 0; i < 8; ++i) { axh[i] = (_Float16)0.0f; axl[i] = (_Float16)0.0f; }
        if (lg < 2) {
            const float* xp = x + (size_t)(m0 + l15) * (TT * FIN) + t * FIN + lg * 8;
            float4 c0 = *(const float4*)xp;
            float4 c1 = *(const float4*)(xp + 4);
            float xv[8] = {c0.x, c0.y, c0.z, c0.w, c1.x, c1.y, c1.z, c1.w};
            #pragma unroll
            for (int i = 0; i < 8; ++i) {
                _Float16 hb = (_Float16)xv[i];
                axh[i] = hb;
                axl[i] = (_Float16)(xv[i] - (float)hb);
            }
        } else if (lg == 2) {
            axh[0] = (_Float16)1.0f;  // bias column
        }
        aR = __builtin_amdgcn_mfma_f32_16x16x32_f16(axh, Bi[0], aR, 0, 0, 0);
        aR = __builtin_amdgcn_mfma_f32_16x16x32_f16(axl, Bi[0], aR, 0, 0, 0);
        aZ = __builtin_amdgcn_mfma_f32_16x16x32_f16(axh, Bi[1], aZ, 0, 0, 0);
        aZ = __builtin_amdgcn_mfma_f32_16x16x32_f16(axl, Bi[1], aZ, 0, 0, 0);
        aI = __builtin_amdgcn_mfma_f32_16x16x32_f16(axh, Bi[2], aI, 0, 0, 0);
        aI = __builtin_amdgcn_mfma_f32_16x16x32_f16(axl, Bi[2], aI, 0, 0, 0);

        // ---- H fragments: direct b128 reads ----
        #pragma unroll
        for (int kf = 0; kf < 4; ++kf) {
            const int ko = kf * 32 + lg * 8;
            f16x8 ahh = *(const f16x8*)&Hhi[rb][l15][ko];
            f16x8 ahl = *(const f16x8*)&Hlo[rb][l15][ko];
            aR = __builtin_amdgcn_mfma_f32_16x16x32_f16(ahh, Bh[0][kf], aR, 0, 0, 0);
            aR = __builtin_amdgcn_mfma_f32_16x16x32_f16(ahl, Bh[0][kf], aR, 0, 0, 0);
            aZ = __builtin_amdgcn_mfma_f32_16x16x32_f16(ahh, Bh[1][kf], aZ, 0, 0, 0);
            aZ = __builtin_amdgcn_mfma_f32_16x16x32_f16(ahl, Bh[1][kf], aZ, 0, 0, 0);
            aH = __builtin_amdgcn_mfma_f32_16x16x32_f16(ahh, Bh[2][kf], aH, 0, 0, 0);
            aH = __builtin_amdgcn_mfma_f32_16x16x32_f16(ahl, Bh[2][kf], aH, 0, 0, 0);
        }

        // ---- gate math in registers (clamp-free tanh; IEEE inf semantics) ----
        #pragma unroll
        for (int p = 0; p < 4; ++p) {
            float r = __builtin_amdgcn_rcpf(1.0f + __expf(-aR[p]));
            float z = __builtin_amdgcn_rcpf(1.0f + __expf(-aZ[p]));
            float pre = fmaf(r, aH[p] + bhn, aI[p]);
            float e2 = __expf(2.0f * pre);          // inf/0 both give correct tanh
            float n = fmaf(-2.0f, __builtin_amdgcn_rcpf(e2 + 1.0f), 1.0f);
            float h = fmaf(z, hprev[p] - n, n);
            hprev[p] = h;
            _Float16 hb = (_Float16)h;
            _Float16 lb = (_Float16)(h - (float)hb);
            const int seq = lg * 4 + p;
            Hhi[wb][seq][u] = *(unsigned short*)&hb;
            Hlo[wb][seq][u] = *(unsigned short*)&lb;
        }
        __syncthreads();
    }

    #pragma unroll
    for (int p = 0; p < 4; ++p)
        temporal[(size_t)(m0 + lg * 4 + p) * HH + u] = hprev[p];
}

// ---------------- fused GCN layer: gather + linear + LayerNorm + ReLU ----------------
__global__ __launch_bounds__(128) void gcn_kernel(
    const float* __restrict__ xin,     // [BB][NN][HH]
    const int* __restrict__ rowptr,    // [NN+1]
    const int* __restrict__ esrc,      // edges sorted by dst
    const float* __restrict__ enorm,
    const float* __restrict__ Wt,      // [HH][HH]  Wt[k][j] = W[j][k]
    const float* __restrict__ bias,
    const float* __restrict__ gma, const float* __restrict__ bta,
    float* __restrict__ out)           // [BB][NN][HH]
{
    const int n = blockIdx.x;
    const int j = threadIdx.x;
    const int beg = rowptr[n], end = rowptr[n + 1];

    float a0 = 0.f, a1 = 0.f, a2 = 0.f, a3 = 0.f;
    int e = beg;
    for (; e + 1 < end; e += 2) {
        int   s0 = esrc[e],   s1 = esrc[e + 1];
        float m0 = enorm[e],  m1 = enorm[e + 1];
        const float* p0 = xin + (size_t)s0 * HH + j;
        const float* p1 = xin + (size_t)s1 * HH + j;
        float v00 = p0[0], v01 = p0[NN*HH], v02 = p0[2*NN*HH], v03 = p0[3*NN*HH];
        float v10 = p1[0], v11 = p1[NN*HH], v12 = p1[2*NN*HH], v13 = p1[3*NN*HH];
        a0 = fmaf(m0, v00, a0); a1 = fmaf(m0, v01, a1);
        a2 = fmaf(m0, v02, a2); a3 = fmaf(m0, v03, a3);
        a0 = fmaf(m1, v10, a0); a1 = fmaf(m1, v11, a1);
        a2 = fmaf(m1, v12, a2); a3 = fmaf(m1, v13, a3);
    }
    if (e < end) {
        int s0 = esrc[e]; float m0 = enorm[e];
        const float* p0 = xin + (size_t)s0 * HH + j;
        a0 = fmaf(m0, p0[0],       a0); a1 = fmaf(m0, p0[NN*HH],   a1);
        a2 = fmaf(m0, p0[2*NN*HH], a2); a3 = fmaf(m0, p0[3*NN*HH], a3);
    }

    __shared__ __align__(16) float agg[BB][HH];
    agg[0][j] = a0; agg[1][j] = a1; agg[2][j] = a2; agg[3][j] = a3;
    __syncthreads();

    const float bj = bias[j];
    float c0 = bj, c1 = bj, c2 = bj, c3 = bj;
    #pragma unroll 4
    for (int k = 0; k < HH; ++k) {
        float w = Wt[k * HH + j];
        c0 = fmaf(w, agg[0][k], c0);
        c1 = fmaf(w, agg[1][k], c1);
        c2 = fmaf(w, agg[2][k], c2);
        c3 = fmaf(w, agg[3][k], c3);
    }

    const int lane = j & 63, wid = j >> 6;
    __shared__ float red[2][BB][2];
    const float gj = gma[j], btj = bta[j];

#define LNRED(cv, b) do { \
        float s1 = (cv), s2 = (cv) * (cv); \
        for (int off = 32; off >= 1; off >>= 1) { s1 += __shfl_down(s1, off); s2 += __shfl_down(s2, off); } \
        if (lane == 0) { red[wid][b][0] = s1; red[wid][b][1] = s2; } \
    } while (0)
    LNRED(c0, 0); LNRED(c1, 1); LNRED(c2, 2); LNRED(c3, 3);
    __syncthreads();

#define LNOUT(cv, b) do { \
        float s1 = red[0][b][0] + red[1][b][0]; \
        float s2 = red[0][b][1] + red[1][b][1]; \
        float mu = s1 * (1.0f / HH); \
        float var = s2 * (1.0f / HH) - mu * mu; \
        float y = ((cv) - mu) * rsqrtf(var + 1e-5f) * gj + btj; \
        out[((size_t)(b) * NN + n) * HH + j] = fmaxf(y, 0.0f); \
    } while (0)
    LNOUT(c0, 0); LNOUT(c1, 1); LNOUT(c2, 2); LNOUT(c3, 3);
#undef LNRED
#undef LNOUT
}

// ---------------- classifier (fused 2-layer MLP) ----------------
__global__ __launch_bounds__(128) void classifier_kernel(
    const float* __restrict__ tin,   // temporal [BN][HH]
    const float* __restrict__ sin_,  // spatial  [BN][HH]
    const float* __restrict__ Wt1,   // [2*HH][HH]
    const float* __restrict__ b1,
    const float* __restrict__ W2,    // [CC][HH]
    const float* __restrict__ b2,
    float* __restrict__ out)         // [BN][CC]
{
    const int j = threadIdx.x;
    const int r0 = blockIdx.x * 8;
    __shared__ __align__(16) float tb[HH][8];
    __shared__ __align__(16) float sb[HH][8];
    __shared__ __align__(16) float h1[HH][8];
    for (int i = j; i < 8 * HH; i += 128) {
        int r = i >> 7, k = i & 127;
        tb[k][r] = tin [(size_t)(r0 + r) * HH + k];
        sb[k][r] = sin_[(size_t)(r0 + r) * HH + k];
    }
    __syncthreads();

    float acc[8];
    float bj = b1[j];
    #pragma unroll
    for (int r = 0; r < 8; ++r) acc[r] = bj;
    #pragma unroll 2
    for (int k = 0; k < HH; ++k) {
        float w = Wt1[k * HH + j];
        float4 a  = *(const float4*)&tb[k][0];
        float4 b4 = *(const float4*)&tb[k][4];
        acc[0] = fmaf(w, a.x,  acc[0]); acc[1] = fmaf(w, a.y,  acc[1]);
        acc[2] = fmaf(w, a.z,  acc[2]); acc[3] = fmaf(w, a.w,  acc[3]);
        acc[4] = fmaf(w, b4.x, acc[4]); acc[5] = fmaf(w, b4.y, acc[5]);
        acc[6] = fmaf(w, b4.z, acc[6]); acc[7] = fmaf(w, b4.w, acc[7]);
    }
    #pragma unroll 2
    for (int k = 0; k < HH; ++k) {
        float w = Wt1[(HH + k) * HH + j];
        float4 a  = *(const float4*)&sb[k][0];
        float4 b4 = *(const float4*)&sb[k][4];
        acc[0] = fmaf(w, a.x,  acc[0]); acc[1] = fmaf(w, a.y,  acc[1]);
        acc[2] = fmaf(w, a.z,  acc[2]); acc[3] = fmaf(w, a.w,  acc[3]);
        acc[4] = fmaf(w, b4.x, acc[4]); acc[5] = fmaf(w, b4.y, acc[5]);
        acc[6] = fmaf(w, b4.z, acc[6]); acc[7] = fmaf(w, b4.w, acc[7]);
    }
    #pragma unroll
    for (int r = 0; r < 8; ++r) h1[j][r] = fmaxf(acc[r], 0.0f);
    __syncthreads();

    if (j < 8 * CC) {
        int r = j / CC, c = j - r * CC;
        float a = b2[c];
        for (int k = 0; k < HH; ++k) a = fmaf(W2[c * HH + k], h1[k][r], a);
        out[(size_t)(r0 + r) * CC + c] = a;
    }
}

// ---------------- launch ----------------
extern "C" void kernel_launch(void* const* d_in, const int* in_sizes, int n_in,
                              void* d_out, int out_size, void* d_ws, size_t ws_size,
                              hipStream_t stream) {
    const float* x    = (const float*)d_in[0];
    const int*   ei   = (const int*)  d_in[1];
    const float* W_ih = (const float*)d_in[2];
    const float* W_hh = (const float*)d_in[3];
    const float* b_ih = (const float*)d_in[4];
    const float* b_hh = (const float*)d_in[5];
    const float* gW1  = (const float*)d_in[6];
    const float* gb1  = (const float*)d_in[7];
    const float* gW2  = (const float*)d_in[8];
    const float* gb2  = (const float*)d_in[9];
    const float* lg1  = (const float*)d_in[10];
    const float* lb1  = (const float*)d_in[11];
    const float* lg2  = (const float*)d_in[12];
    const float* lb2  = (const float*)d_in[13];
    const float* cW1  = (const float*)d_in[14];
    const float* cb1  = (const float*)d_in[15];
    const float* cW2  = (const float*)d_in[16];
    const float* cb2  = (const float*)d_in[17];
    float* out = (float*)d_out;

    float* ws = (float*)d_ws;
    float* Wt_g1 = ws;  ws += 128 * 128;
    float* Wt_g2 = ws;  ws += 128 * 128;
    float* Wt_c1 = ws;  ws += 256 * 128;
    float* dis   = ws;  ws += 2048;
    float* enorm = ws;  ws += EE;
    float* temporal = ws; ws += (size_t)BN * HH;
    float* sA    = ws;  ws += (size_t)BN * HH;
    float* sB    = ws;  ws += (size_t)BN * HH;
    int* ip      = (int*)ws;
    int* cnt     = ip;  ip += 2048;
    int* rowptr  = ip;  ip += 2080;
    int* cursor  = ip;  ip += 2048;
    int* esrc    = ip;  ip += EE;

    const int* srcp = ei;
    const int* dstp = ei + EE;

    hipMemsetAsync(cnt, 0, 2048 * sizeof(int), stream);

    fused_transpose_kernel<<<256, 256, 0, stream>>>(gW1, gW2, cW1, Wt_g1, Wt_g2, Wt_c1);

    cnt_kernel<<<250, 256, 0, stream>>>(dstp, cnt);
    scan_kernel<<<1, 256, 0, stream>>>(cnt, rowptr, cursor, dis);
    csr_fill_kernel<<<250, 256, 0, stream>>>(srcp, dstp, dis, cursor, esrc, enorm);

    gru_mfma_kernel<<<BN / 16, 512, 0, stream>>>(x, W_hh, W_ih, b_ih, b_hh, temporal);

    gcn_kernel<<<NN, 128, 0, stream>>>(temporal, rowptr, esrc, enorm, Wt_g1, gb1, lg1, lb1, sA);
    gcn_kernel<<<NN, 128, 0, stream>>>(sA, rowptr, esrc, enorm, Wt_g2, gb2, lg2, lb2, sB);

    classifier_kernel<<<BN / 8, 128, 0, stream>>>(temporal, sB, Wt_c1, cb1, cW2, cb2, out);
}